// Round 5
// baseline (8636.697 us; speedup 1.0000x reference)
//
#include <hip/hip_runtime.h>

typedef unsigned int u32;
typedef unsigned long long u64;
typedef float f32x2 __attribute__((ext_vector_type(2)));

#define N_PTS 16384
#define N_S   8192
#define NB    10
#define CHID  64
#define COUT  128
#define R2    0.0625f
#define NCELL 4096

// ======================= sort: morton counting sort =======================
__global__ void zero_hist(int* __restrict__ hist) {
  hist[blockIdx.x * 256 + threadIdx.x] = 0;
}

__device__ __forceinline__ u32 spread3(u32 v) {  // 4 bits -> every 3rd bit
  return (v & 1u) | ((v & 2u) << 2) | ((v & 4u) << 4) | ((v & 8u) << 6);
}

__global__ void cell_kernel(const float* __restrict__ pos, int* __restrict__ cellid,
                            int* __restrict__ hist) {
  int i = blockIdx.x * 256 + threadIdx.x;
  float x = pos[3 * i], y = pos[3 * i + 1], z = pos[3 * i + 2];
  u32 ix = (u32)(x * 16.0f); if (ix > 15u) ix = 15u;
  u32 iy = (u32)(y * 16.0f); if (iy > 15u) iy = 15u;
  u32 iz = (u32)(z * 16.0f); if (iz > 15u) iz = 15u;
  u32 c = spread3(ix) | (spread3(iy) << 1) | (spread3(iz) << 2);
  cellid[i] = (int)c;
  atomicAdd(&hist[c], 1);
}

__global__ __launch_bounds__(1024) void scan_kernel(const int* __restrict__ hist,
                                                    int* __restrict__ base) {
  __shared__ int sp[1024];
  int t = threadIdx.x;
  int h0 = hist[4 * t], h1 = hist[4 * t + 1], h2 = hist[4 * t + 2], h3 = hist[4 * t + 3];
  int s = h0 + h1 + h2 + h3;
  int acc = s;
  sp[t] = s;
  __syncthreads();
  for (int off = 1; off < 1024; off <<= 1) {
    int v = (t >= off) ? sp[t - off] : 0;
    __syncthreads();
    acc += v;
    sp[t] = acc;
    __syncthreads();
  }
  int excl = acc - s;
  base[4 * t + 0] = excl;
  base[4 * t + 1] = excl + h0;
  base[4 * t + 2] = excl + h0 + h1;
  base[4 * t + 3] = excl + h0 + h1 + h2;
}

__global__ void scatter_kernel(const float* __restrict__ pos, const int* __restrict__ cellid,
                               int* __restrict__ base, float* __restrict__ xs,
                               float* __restrict__ ys, float* __restrict__ zs,
                               int* __restrict__ oid) {
  int i = blockIdx.x * 256 + threadIdx.x;
  int c = cellid[i];
  int d = atomicAdd(&base[c], 1);
  xs[d] = pos[3 * i]; ys[d] = pos[3 * i + 1]; zs[d] = pos[3 * i + 2];
  oid[d] = i;
}

// ======================= FPS: R21 resubmit (from R20 @ 6.99 ms) ==============
// R20 post-mortem: 16->4 atomic sites bought only -60 cy/iter -> queue-at-the-
// atomic falsified. Residual ~1000 cy/iter attributed to the CORRELATED
// redundant tail: 16 waves in lockstep issue 48 LDS reads + 16 global loads
// post-barrier; requests queue on the single LDS pipe / TA port, and the
// dependent xs[sidx] global (~200cy+queue) sits on every wave's chain.
// R21: owner-push. Each wave publishes its candidate's (x,y,z) PRE-barrier
// into s_wc[k&1][wv]: readlane(wk,63) -> candidate sidx (uniform); owner lane
// (always in-wave: sidx = t*16+J) selects regs via wave-uniform switch(J) and
// does one ds_write_b128. Coords never change -> pruned waves re-push their
// stale-but-valid candidate (no forwarding). Post-barrier: s_g read -> gmax ->
// winning wave = sidx>>10 -> ONE broadcast ds_read_b128 of s_wc. The global
// xs load and s_yz (128 KB) are deleted.
// 2-phase s_wc safety: write pre-barrier(k), read post-barrier(k); next write
// to the same slot is pre-barrier(k+2), i.e. after barrier(k+1), and every
// reader passed barrier(k+1) only after finishing its read. Race-free.
// Unchanged: pk body, prune, dpp wave reduce, 4-site atomic combine, key
// semantics (md<<28 | invoid<<14 | sidx).
#define FPS_T 1024
#define PPT   16

#define PT_LIST(OP) OP(0) OP(1) OP(2) OP(3) OP(4) OP(5) OP(6) OP(7) \
                    OP(8) OP(9) OP(10) OP(11) OP(12) OP(13) OP(14) OP(15)
// OP(G, J0,J1,J2,J3, PA,PB): float4 group G covers points 4G..4G+3, pairs PA=2G, PB=2G+1
#define G4_LIST(OP) OP(0,0,1,2,3,0,1)   OP(1,4,5,6,7,2,3) \
                    OP(2,8,9,10,11,4,5) OP(3,12,13,14,15,6,7)
#define PR_LIST(OP) OP(0) OP(1) OP(2) OP(3) OP(4) OP(5) OP(6) OP(7)

// u64 max via positive-double max (keys < 2^60 -> exponent never all-ones, no
// NaN/inf patterns; positive doubles order == bit order).
__device__ __forceinline__ u64 u64fmax(u64 a, u64 b) {
  double ad = __longlong_as_double((long long)a);
  double bd = __longlong_as_double((long long)b);
  return (u64)(long long)__double_as_longlong(fmax(ad, bd));
}

template <int CTRL, int RM>
__device__ __forceinline__ u64 dppmax(u64 cur) {
  int slo = __builtin_amdgcn_update_dpp(0, (int)(u32)cur, CTRL, RM, 0xf, false);
  int shi = __builtin_amdgcn_update_dpp(0, (int)(u32)(cur >> 32), CTRL, RM, 0xf, false);
  u64 o = ((u64)(u32)shi << 32) | (u32)slo;
  return u64fmax(o, cur);
}

// packed 2xf32 ops (VOP3P, gfx90a+). IEEE RNE per element, no contraction
// possible (opaque asm), denorm mode identical to scalar VALU.
__device__ __forceinline__ f32x2 pk_add(f32x2 a, f32x2 b) {
  f32x2 d;
  asm("v_pk_add_f32 %0, %1, %2" : "=v"(d) : "v"(a), "v"(b));
  return d;
}
__device__ __forceinline__ f32x2 pk_mul(f32x2 a, f32x2 b) {
  f32x2 d;
  asm("v_pk_mul_f32 %0, %1, %2" : "=v"(d) : "v"(a), "v"(b));
  return d;
}

__global__ __launch_bounds__(FPS_T, 4)
void fps_kernel(const float* __restrict__ pos,
                const float* __restrict__ xs,
                const float* __restrict__ ys,
                const float* __restrict__ zs,
                const int* __restrict__ oidv,
                int* __restrict__ idx_out) {
  __shared__ __align__(32) u64 s_g[3][4];   // rotating 4-site global-max slots
  __shared__ float4 s_wc[2][16];            // per-wave candidate coords (2-phase)
  const int t = threadIdx.x;
  const int wv = t >> 6;
  const int base0 = t * PPT;
  const float4* __restrict__ xv = (const float4*)(xs + base0);
  const float4* __restrict__ yv = (const float4*)(ys + base0);
  const float4* __restrict__ zv = (const float4*)(zs + base0);
  const int4*   __restrict__ ov = (const int4*)(oidv + base0);

  // ---- per-point register state: md, x/y/z pairs, key low-word constants
#define DECLP(J) float md##J;
  PT_LIST(DECLP)
#undef DECLP
#define DECLC(J) u32 C##J;
  PT_LIST(DECLC)
#undef DECLC
#define DECLX(P) f32x2 X##P; f32x2 Y##P; f32x2 Z##P;
  PR_LIST(DECLX)
#undef DECLX

  // lane-private chunk bbox lives in registers (constant after init)
  float bnx = 3.4e38f, bxx = -3.4e38f, bny = 3.4e38f, bxy = -3.4e38f,
        bnz = 3.4e38f, bxz = -3.4e38f;

#define INIT4(G, J0, J1, J2, J3, PA, PB) { \
    float4 vx = xv[G], vy = yv[G], vz = zv[G]; int4 vo = ov[G]; \
    md##J0 = 3.402823466e38f; md##J1 = 3.402823466e38f; \
    md##J2 = 3.402823466e38f; md##J3 = 3.402823466e38f; \
    X##PA.x = vx.x; X##PA.y = vx.y; X##PB.x = vx.z; X##PB.y = vx.w; \
    Y##PA.x = vy.x; Y##PA.y = vy.y; Y##PB.x = vy.z; Y##PB.y = vy.w; \
    Z##PA.x = vz.x; Z##PA.y = vz.y; Z##PB.x = vz.z; Z##PB.y = vz.w; \
    C##J0 = ((16383u - (u32)vo.x) << 14) | (u32)(base0 + J0); \
    C##J1 = ((16383u - (u32)vo.y) << 14) | (u32)(base0 + J1); \
    C##J2 = ((16383u - (u32)vo.z) << 14) | (u32)(base0 + J2); \
    C##J3 = ((16383u - (u32)vo.w) << 14) | (u32)(base0 + J3); \
    bnx = fminf(bnx, fminf(fminf(vx.x, vx.y), fminf(vx.z, vx.w))); \
    bxx = fmaxf(bxx, fmaxf(fmaxf(vx.x, vx.y), fmaxf(vx.z, vx.w))); \
    bny = fminf(bny, fminf(fminf(vy.x, vy.y), fminf(vy.z, vy.w))); \
    bxy = fmaxf(bxy, fmaxf(fmaxf(vy.x, vy.y), fmaxf(vy.z, vy.w))); \
    bnz = fminf(bnz, fminf(fminf(vz.x, vz.y), fminf(vz.z, vz.w))); \
    bxz = fmaxf(bxz, fmaxf(fmaxf(vz.x, vz.y), fmaxf(vz.z, vz.w))); }
  G4_LIST(INIT4)
#undef INIT4

  // key = md_bits<<28 | (16383-oid)<<14 | sidx (60 bits). md >= 0 -> float order
  // == bit order. Lex max == numpy argmax (max md, tie -> min oid); sidx trails.
  u64 ckey = 0;
  u64 wklast = 0;                       // per-lane dpp partial; lane 63 = wave max
  float cmaxf = 3.402823466e38f;        // forces all-active first iteration
  float cx = pos[0], cy = pos[1], cz = pos[2];
  if (t == 0) idx_out[0] = 0;
  if (t < 8) s_g[t >> 2][t & 3] = 0;    // zero phase 0,1 sites; phase 2 zeroed at iter 0
  __syncthreads();

  int p = 0;                            // k % 3
  for (int k = 0; k < N_S - 1; ++k) {
    // ---- prune: bbox lower bound vs chunk max-min-dist. Skip-safe: if
    // 0.99*lb2 >= cmaxf no md in this chunk can decrease (1% margin >> fp32
    // rounding of 3-term sums) -> chunk state exactly unchanged.
    float dxl = fmaxf(fmaxf(bnx - cx, cx - bxx), 0.0f);
    float dyl = fmaxf(fmaxf(bny - cy, cy - bxy), 0.0f);
    float dzl = fmaxf(fmaxf(bnz - cz, cz - bxz), 0.0f);
    float lb2 = dxl * dxl + dyl * dyl + dzl * dzl;
    bool act = (0.99f * lb2 < cmaxf);

    if (__ballot(act)) {
      if (act) {
        f32x2 ncx2; ncx2.x = -cx; ncx2.y = -cx;
        f32x2 ncy2; ncy2.x = -cy; ncy2.y = -cy;
        f32x2 ncz2; ncz2.x = -cz; ncz2.y = -cz;
        u64 bkA = 0, bkB = 0;   // even/odd accumulators: halves the dep chain
        // exact numpy arithmetic per element: x+(-c) == x-c (negation exact),
        // pk mul/add are per-op RNE, association (dx2+dy2)+dz2 preserved.
#define UPDP(P, J0, J1) { \
        f32x2 dx2 = pk_add(X##P, ncx2); \
        f32x2 dy2 = pk_add(Y##P, ncy2); \
        f32x2 dz2 = pk_add(Z##P, ncz2); \
        f32x2 sq = pk_add(pk_mul(dx2, dx2), pk_mul(dy2, dy2)); \
        f32x2 d2 = pk_add(sq, pk_mul(dz2, dz2)); \
        float m0 = fminf(md##J0, d2.x); md##J0 = m0; \
        u32 mb0 = __float_as_uint(m0); \
        bkA = u64fmax(bkA, ((u64)(mb0 >> 4) << 32) | ((mb0 << 28) | C##J0)); \
        float m1 = fminf(md##J1, d2.y); md##J1 = m1; \
        u32 mb1 = __float_as_uint(m1); \
        bkB = u64fmax(bkB, ((u64)(mb1 >> 4) << 32) | ((mb1 << 28) | C##J1)); }
        UPDP(0, 0, 1)  UPDP(1, 2, 3)  UPDP(2, 4, 5)  UPDP(3, 6, 7)
        UPDP(4, 8, 9)  UPDP(5, 10, 11) UPDP(6, 12, 13) UPDP(7, 14, 15)
#undef UPDP
        ckey = u64fmax(bkA, bkB);
        cmaxf = __uint_as_float((u32)(ckey >> 28));
      }
      // wave64 max via DPP (row_shr scan + row broadcasts): lane 63 = wave max.
      // Inactive lanes carry their old (still-valid) ckey.
      u64 wk = ckey;
      wk = dppmax<0x111, 0xf>(wk);   // row_shr:1
      wk = dppmax<0x112, 0xf>(wk);   // row_shr:2
      wk = dppmax<0x114, 0xf>(wk);   // row_shr:4
      wk = dppmax<0x118, 0xf>(wk);   // row_shr:8
      wk = dppmax<0x142, 0xa>(wk);   // row_bcast:15 -> rows 1,3
      wk = dppmax<0x143, 0xc>(wk);   // row_bcast:31 -> rows 2,3
      wklast = wk;                   // lane63's value = wave max
    }
    // ---- owner-push: publish this wave's candidate coords (valid whether the
    // wave was active or pruned: coords are immutable, candidate = wklast@63).
    {
      u32 klo = (u32)__builtin_amdgcn_readlane((int)(u32)wklast, 63);
      int wsidx = __builtin_amdgcn_readfirstlane((int)(klo & 16383u)); // uniform
      int ownert = wsidx >> 4;       // owning thread (always in this wave)
      int J = wsidx & 15;            // point index within owner (uniform -> scalar branches)
      float px = 0.f, py = 0.f, pz = 0.f;
      switch (J) {
#define CASE2(P) \
        case 2*P:     px = X##P.x; py = Y##P.x; pz = Z##P.x; break; \
        case 2*P + 1: px = X##P.y; py = Y##P.y; pz = Z##P.y; break;
        CASE2(0) CASE2(1) CASE2(2) CASE2(3) CASE2(4) CASE2(5) CASE2(6) CASE2(7)
#undef CASE2
        default: break;
      }
      if (t == ownert) s_wc[k & 1][wv] = make_float4(px, py, pz, 0.0f);
      // 4-site combine: serialization depth 4; pruned waves republish wklast.
      if ((t & 63) == 63) atomicMax((unsigned long long*)&s_g[p][wv & 3], wklast);
    }
    __syncthreads();

    // two broadcast b128 reads (back-to-back, 2nd latency hidden) + 3-max tree
    ulonglong2 gA = *(const ulonglong2*)&s_g[p][0];
    ulonglong2 gB = *(const ulonglong2*)&s_g[p][2];
    u64 gmax = u64fmax(u64fmax(gA.x, gA.y), u64fmax(gB.x, gB.y));
    // zero the phase used at k+2: its last readers were pre-barrier(k+1), its
    // next writers are post-barrier(k+2). Race-free (same proof as R19).
    int zslot = (p == 0) ? 2 : p - 1;
    if (t < 4) s_g[zslot][t] = 0;
    int sidx = (int)(gmax & 16383u);
    if (t == 0) idx_out[k + 1] = 16383 - (int)((gmax >> 14) & 16383u);
    // next center: ONE broadcast b128 read from the winning wave's pushed
    // coords (winning wave id = sidx>>10 since sidx = t*16+J).
    float4 cw = s_wc[k & 1][sidx >> 10];
    cx = cw.x;
    cy = cw.y;
    cz = cw.z;
    p = (p == 2) ? 0 : p + 1;
  }
}

// ======================= zero the tail rows [N_S, N_PTS) =======================
__global__ void zero_tail(float4* __restrict__ outv, int count) {
  int i = blockIdx.x * blockDim.x + threadIdx.x;
  if (i < count) outv[i] = make_float4(0.f, 0.f, 0.f, 0.f);
}

// ======================= kNN: 8-way split + exact lex merge =======================
#define KNN_T  256   // 32 centers x 8 splits
#define KTILE  1024

__global__ __launch_bounds__(KNN_T) void knn_kernel(const float* __restrict__ pos,
                                                    const int* __restrict__ fps_idx,
                                                    int* __restrict__ src_out,
                                                    int* __restrict__ valid_out) {
  __shared__ float4 s_p[KTILE];   // packed (x,y,z,0): 1 ds_read_b128 per point
  __shared__ float spd[32][8][NB];
  __shared__ int   spi[32][8][NB];
  const int t = threadIdx.x;
  const int sp = t >> 5;
  const int cl = t & 31;
  const int i = blockIdx.x * 32 + cl;
  const int ci = fps_idx[i];
  const float cx = pos[3 * ci], cy = pos[3 * ci + 1], cz = pos[3 * ci + 2];
  float nd[NB]; int ni[NB];
#pragma unroll
  for (int q = 0; q < NB; ++q) { nd[q] = 3.402823466e38f; ni[q] = 0x7fffffff; }

  for (int base = 0; base < N_PTS; base += KTILE) {
    __syncthreads();
    for (int j = t; j < KTILE; j += KNN_T) {
      int pnt = base + j;
      s_p[j] = make_float4(pos[3 * pnt], pos[3 * pnt + 1], pos[3 * pnt + 2], 0.f);
    }
    __syncthreads();
    for (int j = sp; j < KTILE; j += 8) {
      float4 q4 = s_p[j];
      float dx = __fsub_rn(cx, q4.x);
      float dy = __fsub_rn(cy, q4.y);
      float dz = __fsub_rn(cz, q4.z);
      float d2 = __fadd_rn(__fadd_rn(__fmul_rn(dx, dx), __fmul_rn(dy, dy)), __fmul_rn(dz, dz));
      if (d2 < nd[NB - 1]) {
        float cd = d2; int cp = base + j;
#pragma unroll
        for (int q = 0; q < NB; ++q) {
          bool sw = (cd < nd[q]) || (cd == nd[q] && cp < ni[q]);
          if (sw) { float td = nd[q]; int tp = ni[q]; nd[q] = cd; ni[q] = cp; cd = td; cp = tp; }
        }
      }
    }
  }
#pragma unroll
  for (int q = 0; q < NB; ++q) { spd[cl][sp][q] = nd[q]; spi[cl][sp][q] = ni[q]; }
  __syncthreads();
  if (sp == 0) {
    int cur[8];
#pragma unroll
    for (int s = 0; s < 8; ++s) cur[s] = 0;
    int vb = 0;
    for (int q = 0; q < NB; ++q) {
      float bd = 3.402823466e38f; int bi = 0x7fffffff; int bsl = 0;
#pragma unroll
      for (int s = 0; s < 8; ++s) {
        float d = spd[cl][s][cur[s]]; int id = spi[cl][s][cur[s]];
        if (d < bd || (d == bd && id < bi)) { bd = d; bi = id; bsl = s; }
      }
#pragma unroll
      for (int s = 0; s < 8; ++s) cur[s] += (s == bsl) ? 1 : 0;
      src_out[i * NB + q] = bi;
      if (bd <= R2) vb |= (1 << q);
    }
    valid_out[i] = vb;
  }
}

// ======================= MLP + masked max-pool =======================
#define MLP_T 128

__global__ __launch_bounds__(MLP_T) void mlp_kernel(const float* __restrict__ pos,
                                                    const int* __restrict__ src,
                                                    const int* __restrict__ valid,
                                                    const float* __restrict__ W1,
                                                    const float* __restrict__ b1,
                                                    const float* __restrict__ W2,
                                                    const float* __restrict__ b2,
                                                    float* __restrict__ out) {
  __shared__ float sW2[CHID * COUT];
  __shared__ float sW1[3 * CHID];
  __shared__ float sb1[CHID];
  __shared__ float sh1[NB][CHID];
  __shared__ float srel[NB][3];
  __shared__ int   svalid;
  const int t = threadIdx.x;
  const int i = blockIdx.x;

  for (int e = t; e < CHID * COUT; e += MLP_T) sW2[e] = W2[e];
  for (int e = t; e < 3 * CHID; e += MLP_T) sW1[e] = W1[e];
  if (t < CHID) sb1[t] = b1[t];
  if (t < NB) {
    int s = src[i * NB + t];
    // NOTE: reference subtracts pos_i = pos[:s] (row i), NOT the sampled center
    srel[t][0] = pos[3 * s + 0] - pos[3 * i + 0];
    srel[t][1] = pos[3 * s + 1] - pos[3 * i + 1];
    srel[t][2] = pos[3 * s + 2] - pos[3 * i + 2];
  }
  if (t == 0) svalid = valid[i];
  __syncthreads();

  for (int e = t; e < NB * CHID; e += MLP_T) {
    int n = e >> 6, kk = e & 63;
    float a = sb1[kk] + srel[n][0] * sW1[kk] + srel[n][1] * sW1[64 + kk] + srel[n][2] * sW1[128 + kk];
    sh1[n][kk] = fmaxf(a, 0.0f);
  }
  __syncthreads();

  const int vmask = svalid;
  const float bb = b2[t];
  float m = 0.0f;
  bool any = false;
  for (int n = 0; n < NB; ++n) {
    if (vmask & (1 << n)) {
      float acc = bb;
      for (int kk = 0; kk < CHID; ++kk) acc += sh1[n][kk] * sW2[kk * COUT + t];
      m = any ? fmaxf(m, acc) : acc;
      any = true;
    }
  }
  out[i * COUT + t] = any ? m : 0.0f;
}

// ======================= launch =======================
extern "C" void kernel_launch(void* const* d_in, const int* in_sizes, int n_in,
                              void* d_out, int out_size, void* d_ws, size_t ws_size,
                              hipStream_t stream) {
  (void)in_sizes; (void)n_in; (void)out_size; (void)ws_size;
  const float* pos = (const float*)d_in[0];
  const float* W1 = (const float*)d_in[2];
  const float* b1 = (const float*)d_in[3];
  const float* W2 = (const float*)d_in[4];
  const float* b2 = (const float*)d_in[5];
  float* out = (float*)d_out;

  char* ws = (char*)d_ws;
  int*   idx   = (int*)ws;                 ws += (size_t)N_S * 4;          // 32 KB
  int*   src   = (int*)ws;                 ws += (size_t)N_S * NB * 4;     // 320 KB
  int*   valid = (int*)ws;                 ws += (size_t)N_S * 4;          // 32 KB
  float* xs    = (float*)ws;               ws += (size_t)N_PTS * 4;        // 64 KB
  float* ys    = (float*)ws;               ws += (size_t)N_PTS * 4;
  float* zs    = (float*)ws;               ws += (size_t)N_PTS * 4;
  int*   oid   = (int*)ws;                 ws += (size_t)N_PTS * 4;
  // sort temporaries alias the src region (sort completes before knn writes src)
  int* cellid = src;                 // N_PTS ints = 64 KB  (src region is 320 KB)
  int* hist   = src + N_PTS;         // NCELL ints = 16 KB
  int* basebuf= src + N_PTS + NCELL; // NCELL ints = 16 KB

  zero_hist<<<NCELL / 256, 256, 0, stream>>>(hist);
  cell_kernel<<<N_PTS / 256, 256, 0, stream>>>(pos, cellid, hist);
  scan_kernel<<<1, 1024, 0, stream>>>(hist, basebuf);
  scatter_kernel<<<N_PTS / 256, 256, 0, stream>>>(pos, cellid, basebuf, xs, ys, zs, oid);
  fps_kernel<<<1, FPS_T, 0, stream>>>(pos, xs, ys, zs, oid, idx);
  {
    int count = (N_PTS - N_S) * COUT / 4;
    zero_tail<<<(count + 255) / 256, 256, 0, stream>>>((float4*)(out + (size_t)N_S * COUT), count);
  }
  knn_kernel<<<N_S / 32, KNN_T, 0, stream>>>(pos, idx, src, valid);
  mlp_kernel<<<N_S, MLP_T, 0, stream>>>(pos, src, valid, W1, b1, W2, b2, out);
}

// Round 6
// 8006.248 us; speedup vs baseline: 1.0787x; 1.0787x over previous
//
#include <hip/hip_runtime.h>

typedef unsigned int u32;
typedef unsigned long long u64;
typedef float f32x2 __attribute__((ext_vector_type(2)));

#define N_PTS 16384
#define N_S   8192
#define NB    10
#define CHID  64
#define COUT  128
#define R2    0.0625f
#define NCELL 4096

// ======================= sort: morton counting sort =======================
__global__ void zero_hist(int* __restrict__ hist) {
  hist[blockIdx.x * 256 + threadIdx.x] = 0;
}

__device__ __forceinline__ u32 spread3(u32 v) {  // 4 bits -> every 3rd bit
  return (v & 1u) | ((v & 2u) << 2) | ((v & 4u) << 4) | ((v & 8u) << 6);
}

__global__ void cell_kernel(const float* __restrict__ pos, int* __restrict__ cellid,
                            int* __restrict__ hist) {
  int i = blockIdx.x * 256 + threadIdx.x;
  float x = pos[3 * i], y = pos[3 * i + 1], z = pos[3 * i + 2];
  u32 ix = (u32)(x * 16.0f); if (ix > 15u) ix = 15u;
  u32 iy = (u32)(y * 16.0f); if (iy > 15u) iy = 15u;
  u32 iz = (u32)(z * 16.0f); if (iz > 15u) iz = 15u;
  u32 c = spread3(ix) | (spread3(iy) << 1) | (spread3(iz) << 2);
  cellid[i] = (int)c;
  atomicAdd(&hist[c], 1);
}

__global__ __launch_bounds__(1024) void scan_kernel(const int* __restrict__ hist,
                                                    int* __restrict__ base) {
  __shared__ int sp[1024];
  int t = threadIdx.x;
  int h0 = hist[4 * t], h1 = hist[4 * t + 1], h2 = hist[4 * t + 2], h3 = hist[4 * t + 3];
  int s = h0 + h1 + h2 + h3;
  int acc = s;
  sp[t] = s;
  __syncthreads();
  for (int off = 1; off < 1024; off <<= 1) {
    int v = (t >= off) ? sp[t - off] : 0;
    __syncthreads();
    acc += v;
    sp[t] = acc;
    __syncthreads();
  }
  int excl = acc - s;
  base[4 * t + 0] = excl;
  base[4 * t + 1] = excl + h0;
  base[4 * t + 2] = excl + h0 + h1;
  base[4 * t + 3] = excl + h0 + h1 + h2;
}

__global__ void scatter_kernel(const float* __restrict__ pos, const int* __restrict__ cellid,
                               int* __restrict__ base, float* __restrict__ xs,
                               float* __restrict__ ys, float* __restrict__ zs,
                               int* __restrict__ oid) {
  int i = blockIdx.x * 256 + threadIdx.x;
  int c = cellid[i];
  int d = atomicAdd(&base[c], 1);
  xs[d] = pos[3 * i]; ys[d] = pos[3 * i + 1]; zs[d] = pos[3 * i + 2];
  oid[d] = i;
}

// ======================= FPS: R22 (from R20 @ 6.99 ms; R21 7.56 regressed) ===
// R21 post-mortem: owner-push moved tail traffic ONTO the LDS pipe (+16 b128
// reads, +readlane/switch/write chain) -> +167 cy/iter. Pipe audit of R20's
// tail: 32 b128 (s_g) + 16 b64 (s_yz) + 16 u64 atomics + zero-writes ~= 700 cy
// of serialized LDS-pipe occupancy per iteration -- the previously-missing
// ~1000 cy. R22 drains the LDS pipe in the tail:
//  - publish: lane63 plain ds_write_b64 to s_k[k&1][wv] (16x ~6cy, no RMW).
//    Atomics, 3-slot rotation, zero-writes DELETED. Pruned waves write wklast
//    (register, still-valid: md monotone). All 16 slots written every iter.
//  - reduce: ONE vector ds_read_b64 per wave (s_k[k&1][t&15]: 16 addrs = one
//    bank sweep, 4x replicated broadcast, conflict-free) + 4-stage row_ror
//    dppmax + 2 readfirstlane (R16's proven pattern).
//  - center fetch off the LDS pipe: sidx is SGPR-uniform -> cx/cy/cz via
//    scalar loads from sorted xs/ys/zs (SMEM/L2 path, 3 parallel ~200cy).
//    s_yz (128 KB) DELETED.
// Parity safety: write [k&1] pre-barrier(k), read post-barrier(k); next write
// to the same slot is pre-barrier(k+2), after barrier(k+1); readers finished
// before they arrived at barrier(k+1). Race-free.
// Unchanged: pk body, prune, 6-stage dpp wave reduce, key semantics.
#define FPS_T 1024
#define PPT   16

#define PT_LIST(OP) OP(0) OP(1) OP(2) OP(3) OP(4) OP(5) OP(6) OP(7) \
                    OP(8) OP(9) OP(10) OP(11) OP(12) OP(13) OP(14) OP(15)
// OP(G, J0,J1,J2,J3, PA,PB): float4 group G covers points 4G..4G+3, pairs PA=2G, PB=2G+1
#define G4_LIST(OP) OP(0,0,1,2,3,0,1)   OP(1,4,5,6,7,2,3) \
                    OP(2,8,9,10,11,4,5) OP(3,12,13,14,15,6,7)
#define PR_LIST(OP) OP(0) OP(1) OP(2) OP(3) OP(4) OP(5) OP(6) OP(7)

// u64 max via positive-double max (keys < 2^60 -> exponent never all-ones, no
// NaN/inf patterns; positive doubles order == bit order).
__device__ __forceinline__ u64 u64fmax(u64 a, u64 b) {
  double ad = __longlong_as_double((long long)a);
  double bd = __longlong_as_double((long long)b);
  return (u64)(long long)__double_as_longlong(fmax(ad, bd));
}

template <int CTRL, int RM>
__device__ __forceinline__ u64 dppmax(u64 cur) {
  int slo = __builtin_amdgcn_update_dpp(0, (int)(u32)cur, CTRL, RM, 0xf, false);
  int shi = __builtin_amdgcn_update_dpp(0, (int)(u32)(cur >> 32), CTRL, RM, 0xf, false);
  u64 o = ((u64)(u32)shi << 32) | (u32)slo;
  return u64fmax(o, cur);
}

// packed 2xf32 ops (VOP3P, gfx90a+). IEEE RNE per element, no contraction
// possible (opaque asm), denorm mode identical to scalar VALU.
__device__ __forceinline__ f32x2 pk_add(f32x2 a, f32x2 b) {
  f32x2 d;
  asm("v_pk_add_f32 %0, %1, %2" : "=v"(d) : "v"(a), "v"(b));
  return d;
}
__device__ __forceinline__ f32x2 pk_mul(f32x2 a, f32x2 b) {
  f32x2 d;
  asm("v_pk_mul_f32 %0, %1, %2" : "=v"(d) : "v"(a), "v"(b));
  return d;
}

__global__ __launch_bounds__(FPS_T, 4)
void fps_kernel(const float* __restrict__ pos,
                const float* __restrict__ xs,
                const float* __restrict__ ys,
                const float* __restrict__ zs,
                const int* __restrict__ oidv,
                int* __restrict__ idx_out) {
  __shared__ u64 s_k[2][16];                // parity double-buffer of wave keys
  const int t = threadIdx.x;
  const int wv = t >> 6;
  const int base0 = t * PPT;
  const float4* __restrict__ xv = (const float4*)(xs + base0);
  const float4* __restrict__ yv = (const float4*)(ys + base0);
  const float4* __restrict__ zv = (const float4*)(zs + base0);
  const int4*   __restrict__ ov = (const int4*)(oidv + base0);

  // ---- per-point register state: md, x/y/z pairs, key low-word constants
#define DECLP(J) float md##J;
  PT_LIST(DECLP)
#undef DECLP
#define DECLC(J) u32 C##J;
  PT_LIST(DECLC)
#undef DECLC
#define DECLX(P) f32x2 X##P; f32x2 Y##P; f32x2 Z##P;
  PR_LIST(DECLX)
#undef DECLX

  // lane-private chunk bbox lives in registers (constant after init)
  float bnx = 3.4e38f, bxx = -3.4e38f, bny = 3.4e38f, bxy = -3.4e38f,
        bnz = 3.4e38f, bxz = -3.4e38f;

#define INIT4(G, J0, J1, J2, J3, PA, PB) { \
    float4 vx = xv[G], vy = yv[G], vz = zv[G]; int4 vo = ov[G]; \
    md##J0 = 3.402823466e38f; md##J1 = 3.402823466e38f; \
    md##J2 = 3.402823466e38f; md##J3 = 3.402823466e38f; \
    X##PA.x = vx.x; X##PA.y = vx.y; X##PB.x = vx.z; X##PB.y = vx.w; \
    Y##PA.x = vy.x; Y##PA.y = vy.y; Y##PB.x = vy.z; Y##PB.y = vy.w; \
    Z##PA.x = vz.x; Z##PA.y = vz.y; Z##PB.x = vz.z; Z##PB.y = vz.w; \
    C##J0 = ((16383u - (u32)vo.x) << 14) | (u32)(base0 + J0); \
    C##J1 = ((16383u - (u32)vo.y) << 14) | (u32)(base0 + J1); \
    C##J2 = ((16383u - (u32)vo.z) << 14) | (u32)(base0 + J2); \
    C##J3 = ((16383u - (u32)vo.w) << 14) | (u32)(base0 + J3); \
    bnx = fminf(bnx, fminf(fminf(vx.x, vx.y), fminf(vx.z, vx.w))); \
    bxx = fmaxf(bxx, fmaxf(fmaxf(vx.x, vx.y), fmaxf(vx.z, vx.w))); \
    bny = fminf(bny, fminf(fminf(vy.x, vy.y), fminf(vy.z, vy.w))); \
    bxy = fmaxf(bxy, fmaxf(fmaxf(vy.x, vy.y), fmaxf(vy.z, vy.w))); \
    bnz = fminf(bnz, fminf(fminf(vz.x, vz.y), fminf(vz.z, vz.w))); \
    bxz = fmaxf(bxz, fmaxf(fmaxf(vz.x, vz.y), fmaxf(vz.z, vz.w))); }
  G4_LIST(INIT4)
#undef INIT4

  // key = md_bits<<28 | (16383-oid)<<14 | sidx (60 bits). md >= 0 -> float order
  // == bit order. Lex max == numpy argmax (max md, tie -> min oid); sidx trails.
  u64 ckey = 0;
  u64 wklast = 0;                       // per-lane dpp partial; lane 63 = wave max
  float cmaxf = 3.402823466e38f;        // forces all-active first iteration
  float cx = pos[0], cy = pos[1], cz = pos[2];
  if (t == 0) idx_out[0] = 0;
  __syncthreads();

  for (int k = 0; k < N_S - 1; ++k) {
    // ---- prune: bbox lower bound vs chunk max-min-dist. Skip-safe: if
    // 0.99*lb2 >= cmaxf no md in this chunk can decrease (1% margin >> fp32
    // rounding of 3-term sums) -> chunk state exactly unchanged.
    float dxl = fmaxf(fmaxf(bnx - cx, cx - bxx), 0.0f);
    float dyl = fmaxf(fmaxf(bny - cy, cy - bxy), 0.0f);
    float dzl = fmaxf(fmaxf(bnz - cz, cz - bxz), 0.0f);
    float lb2 = dxl * dxl + dyl * dyl + dzl * dzl;
    bool act = (0.99f * lb2 < cmaxf);

    if (__ballot(act)) {
      if (act) {
        f32x2 ncx2; ncx2.x = -cx; ncx2.y = -cx;
        f32x2 ncy2; ncy2.x = -cy; ncy2.y = -cy;
        f32x2 ncz2; ncz2.x = -cz; ncz2.y = -cz;
        u64 bkA = 0, bkB = 0;   // even/odd accumulators: halves the dep chain
        // exact numpy arithmetic per element: x+(-c) == x-c (negation exact),
        // pk mul/add are per-op RNE, association (dx2+dy2)+dz2 preserved.
#define UPDP(P, J0, J1) { \
        f32x2 dx2 = pk_add(X##P, ncx2); \
        f32x2 dy2 = pk_add(Y##P, ncy2); \
        f32x2 dz2 = pk_add(Z##P, ncz2); \
        f32x2 sq = pk_add(pk_mul(dx2, dx2), pk_mul(dy2, dy2)); \
        f32x2 d2 = pk_add(sq, pk_mul(dz2, dz2)); \
        float m0 = fminf(md##J0, d2.x); md##J0 = m0; \
        u32 mb0 = __float_as_uint(m0); \
        bkA = u64fmax(bkA, ((u64)(mb0 >> 4) << 32) | ((mb0 << 28) | C##J0)); \
        float m1 = fminf(md##J1, d2.y); md##J1 = m1; \
        u32 mb1 = __float_as_uint(m1); \
        bkB = u64fmax(bkB, ((u64)(mb1 >> 4) << 32) | ((mb1 << 28) | C##J1)); }
        UPDP(0, 0, 1)  UPDP(1, 2, 3)  UPDP(2, 4, 5)  UPDP(3, 6, 7)
        UPDP(4, 8, 9)  UPDP(5, 10, 11) UPDP(6, 12, 13) UPDP(7, 14, 15)
#undef UPDP
        ckey = u64fmax(bkA, bkB);
        cmaxf = __uint_as_float((u32)(ckey >> 28));
      }
      // wave64 max via DPP (row_shr scan + row broadcasts): lane 63 = wave max.
      // Inactive lanes carry their old (still-valid) ckey.
      u64 wk = ckey;
      wk = dppmax<0x111, 0xf>(wk);   // row_shr:1
      wk = dppmax<0x112, 0xf>(wk);   // row_shr:2
      wk = dppmax<0x114, 0xf>(wk);   // row_shr:4
      wk = dppmax<0x118, 0xf>(wk);   // row_shr:8
      wk = dppmax<0x142, 0xa>(wk);   // row_bcast:15 -> rows 1,3
      wk = dppmax<0x143, 0xc>(wk);   // row_bcast:31 -> rows 2,3
      wklast = wk;                   // lane63's value = wave max
    }
    // publish: single-lane plain write (no RMW). Pruned waves re-publish
    // wklast (exact: their mds unchanged, md monotone non-increasing).
    if ((t & 63) == 63) s_k[k & 1][wv] = wklast;
    __syncthreads();

    // ---- all waves redundantly reduce the 16 wave keys: ONE vector b64 read
    // (16 addrs, 4x replicated broadcast, bank-sweep, conflict-free) + 4-stage
    // row_ror dppmax (period-16) -> every lane of row 0 holds the global max.
    u64 gk = s_k[k & 1][t & 15];
    gk = dppmax<0x121, 0xf>(gk);   // row_ror:1
    gk = dppmax<0x122, 0xf>(gk);   // row_ror:2
    gk = dppmax<0x124, 0xf>(gk);   // row_ror:4
    gk = dppmax<0x128, 0xf>(gk);   // row_ror:8
    u32 glo = (u32)__builtin_amdgcn_readfirstlane((int)(u32)gk);
    u32 ghi = (u32)__builtin_amdgcn_readfirstlane((int)(u32)(gk >> 32));
    u64 gmax = ((u64)ghi << 32) | glo;
    int sidx = (int)(gmax & 16383u);      // SGPR (from readfirstlane chain)
    if (t == 0) idx_out[k + 1] = 16383 - (int)((gmax >> 14) & 16383u);
    // next center: sidx is uniform -> scalar loads from sorted xs/ys/zs
    // (SMEM/L2 path, 3 parallel, off the LDS pipe).
    cx = xs[sidx];
    cy = ys[sidx];
    cz = zs[sidx];
  }
}

// ======================= zero the tail rows [N_S, N_PTS) =======================
__global__ void zero_tail(float4* __restrict__ outv, int count) {
  int i = blockIdx.x * blockDim.x + threadIdx.x;
  if (i < count) outv[i] = make_float4(0.f, 0.f, 0.f, 0.f);
}

// ======================= kNN: 8-way split + exact lex merge =======================
#define KNN_T  256   // 32 centers x 8 splits
#define KTILE  1024

__global__ __launch_bounds__(KNN_T) void knn_kernel(const float* __restrict__ pos,
                                                    const int* __restrict__ fps_idx,
                                                    int* __restrict__ src_out,
                                                    int* __restrict__ valid_out) {
  __shared__ float sx[KTILE], sy[KTILE], sz[KTILE];
  __shared__ float spd[32][8][NB];
  __shared__ int   spi[32][8][NB];
  const int t = threadIdx.x;
  const int sp = t >> 5;
  const int cl = t & 31;
  const int i = blockIdx.x * 32 + cl;
  const int ci = fps_idx[i];
  const float cx = pos[3 * ci], cy = pos[3 * ci + 1], cz = pos[3 * ci + 2];
  float nd[NB]; int ni[NB];
#pragma unroll
  for (int q = 0; q < NB; ++q) { nd[q] = 3.402823466e38f; ni[q] = 0x7fffffff; }

  for (int base = 0; base < N_PTS; base += KTILE) {
    __syncthreads();
    for (int j = t; j < KTILE; j += KNN_T) {
      int pnt = base + j;
      sx[j] = pos[3 * pnt]; sy[j] = pos[3 * pnt + 1]; sz[j] = pos[3 * pnt + 2];
    }
    __syncthreads();
    for (int j = sp; j < KTILE; j += 8) {
      float dx = __fsub_rn(cx, sx[j]);
      float dy = __fsub_rn(cy, sy[j]);
      float dz = __fsub_rn(cz, sz[j]);
      float d2 = __fadd_rn(__fadd_rn(__fmul_rn(dx, dx), __fmul_rn(dy, dy)), __fmul_rn(dz, dz));
      if (d2 < nd[NB - 1]) {
        float cd = d2; int cp = base + j;
#pragma unroll
        for (int q = 0; q < NB; ++q) {
          bool sw = (cd < nd[q]) || (cd == nd[q] && cp < ni[q]);
          if (sw) { float td = nd[q]; int tp = ni[q]; nd[q] = cd; ni[q] = cp; cd = td; cp = tp; }
        }
      }
    }
  }
#pragma unroll
  for (int q = 0; q < NB; ++q) { spd[cl][sp][q] = nd[q]; spi[cl][sp][q] = ni[q]; }
  __syncthreads();
  if (sp == 0) {
    int cur[8];
#pragma unroll
    for (int s = 0; s < 8; ++s) cur[s] = 0;
    int vb = 0;
    for (int q = 0; q < NB; ++q) {
      float bd = 3.402823466e38f; int bi = 0x7fffffff; int bsl = 0;
#pragma unroll
      for (int s = 0; s < 8; ++s) {
        float d = spd[cl][s][cur[s]]; int id = spi[cl][s][cur[s]];
        if (d < bd || (d == bd && id < bi)) { bd = d; bi = id; bsl = s; }
      }
#pragma unroll
      for (int s = 0; s < 8; ++s) cur[s] += (s == bsl) ? 1 : 0;
      src_out[i * NB + q] = bi;
      if (bd <= R2) vb |= (1 << q);
    }
    valid_out[i] = vb;
  }
}

// ======================= MLP + masked max-pool =======================
#define MLP_T 128

__global__ __launch_bounds__(MLP_T) void mlp_kernel(const float* __restrict__ pos,
                                                    const int* __restrict__ src,
                                                    const int* __restrict__ valid,
                                                    const float* __restrict__ W1,
                                                    const float* __restrict__ b1,
                                                    const float* __restrict__ W2,
                                                    const float* __restrict__ b2,
                                                    float* __restrict__ out) {
  __shared__ float sW2[CHID * COUT];
  __shared__ float sW1[3 * CHID];
  __shared__ float sb1[CHID];
  __shared__ float sh1[NB][CHID];
  __shared__ float srel[NB][3];
  __shared__ int   svalid;
  const int t = threadIdx.x;
  const int i = blockIdx.x;

  for (int e = t; e < CHID * COUT; e += MLP_T) sW2[e] = W2[e];
  for (int e = t; e < 3 * CHID; e += MLP_T) sW1[e] = W1[e];
  if (t < CHID) sb1[t] = b1[t];
  if (t < NB) {
    int s = src[i * NB + t];
    // NOTE: reference subtracts pos_i = pos[:s] (row i), NOT the sampled center
    srel[t][0] = pos[3 * s + 0] - pos[3 * i + 0];
    srel[t][1] = pos[3 * s + 1] - pos[3 * i + 1];
    srel[t][2] = pos[3 * s + 2] - pos[3 * i + 2];
  }
  if (t == 0) svalid = valid[i];
  __syncthreads();

  for (int e = t; e < NB * CHID; e += MLP_T) {
    int n = e >> 6, kk = e & 63;
    float a = sb1[kk] + srel[n][0] * sW1[kk] + srel[n][1] * sW1[64 + kk] + srel[n][2] * sW1[128 + kk];
    sh1[n][kk] = fmaxf(a, 0.0f);
  }
  __syncthreads();

  const int vmask = svalid;
  const float bb = b2[t];
  float m = 0.0f;
  bool any = false;
  for (int n = 0; n < NB; ++n) {
    if (vmask & (1 << n)) {
      float acc = bb;
      for (int kk = 0; kk < CHID; ++kk) acc += sh1[n][kk] * sW2[kk * COUT + t];
      m = any ? fmaxf(m, acc) : acc;
      any = true;
    }
  }
  out[i * COUT + t] = any ? m : 0.0f;
}

// ======================= launch =======================
extern "C" void kernel_launch(void* const* d_in, const int* in_sizes, int n_in,
                              void* d_out, int out_size, void* d_ws, size_t ws_size,
                              hipStream_t stream) {
  (void)in_sizes; (void)n_in; (void)out_size; (void)ws_size;
  const float* pos = (const float*)d_in[0];
  const float* W1 = (const float*)d_in[2];
  const float* b1 = (const float*)d_in[3];
  const float* W2 = (const float*)d_in[4];
  const float* b2 = (const float*)d_in[5];
  float* out = (float*)d_out;

  char* ws = (char*)d_ws;
  int*   idx   = (int*)ws;                 ws += (size_t)N_S * 4;          // 32 KB
  int*   src   = (int*)ws;                 ws += (size_t)N_S * NB * 4;     // 320 KB
  int*   valid = (int*)ws;                 ws += (size_t)N_S * 4;          // 32 KB
  float* xs    = (float*)ws;               ws += (size_t)N_PTS * 4;        // 64 KB
  float* ys    = (float*)ws;               ws += (size_t)N_PTS * 4;
  float* zs    = (float*)ws;               ws += (size_t)N_PTS * 4;
  int*   oid   = (int*)ws;                 ws += (size_t)N_PTS * 4;
  // sort temporaries alias the src region (sort completes before knn writes src)
  int* cellid = src;                 // N_PTS ints = 64 KB  (src region is 320 KB)
  int* hist   = src + N_PTS;         // NCELL ints = 16 KB
  int* basebuf= src + N_PTS + NCELL; // NCELL ints = 16 KB

  zero_hist<<<NCELL / 256, 256, 0, stream>>>(hist);
  cell_kernel<<<N_PTS / 256, 256, 0, stream>>>(pos, cellid, hist);
  scan_kernel<<<1, 1024, 0, stream>>>(hist, basebuf);
  scatter_kernel<<<N_PTS / 256, 256, 0, stream>>>(pos, cellid, basebuf, xs, ys, zs, oid);
  fps_kernel<<<1, FPS_T, 0, stream>>>(pos, xs, ys, zs, oid, idx);
  {
    int count = (N_PTS - N_S) * COUT / 4;
    zero_tail<<<(count + 255) / 256, 256, 0, stream>>>((float4*)(out + (size_t)N_S * COUT), count);
  }
  knn_kernel<<<N_S / 32, KNN_T, 0, stream>>>(pos, idx, src, valid);
  mlp_kernel<<<N_S, MLP_T, 0, stream>>>(pos, src, valid, W1, b1, W2, b2, out);
}

// Round 7
// 7632.536 us; speedup vs baseline: 1.1316x; 1.0490x over previous
//
#include <hip/hip_runtime.h>

typedef unsigned int u32;
typedef unsigned long long u64;
typedef float f32x2 __attribute__((ext_vector_type(2)));

#define N_PTS 16384
#define N_S   8192
#define NB    10
#define CHID  64
#define COUT  128
#define R2    0.0625f
#define NCELL 4096

// ======================= sort: morton counting sort =======================
__global__ void zero_hist(int* __restrict__ hist) {
  hist[blockIdx.x * 256 + threadIdx.x] = 0;
}

__device__ __forceinline__ u32 spread3(u32 v) {  // 4 bits -> every 3rd bit
  return (v & 1u) | ((v & 2u) << 2) | ((v & 4u) << 4) | ((v & 8u) << 6);
}

__global__ void cell_kernel(const float* __restrict__ pos, int* __restrict__ cellid,
                            int* __restrict__ hist) {
  int i = blockIdx.x * 256 + threadIdx.x;
  float x = pos[3 * i], y = pos[3 * i + 1], z = pos[3 * i + 2];
  u32 ix = (u32)(x * 16.0f); if (ix > 15u) ix = 15u;
  u32 iy = (u32)(y * 16.0f); if (iy > 15u) iy = 15u;
  u32 iz = (u32)(z * 16.0f); if (iz > 15u) iz = 15u;
  u32 c = spread3(ix) | (spread3(iy) << 1) | (spread3(iz) << 2);
  cellid[i] = (int)c;
  atomicAdd(&hist[c], 1);
}

__global__ __launch_bounds__(1024) void scan_kernel(const int* __restrict__ hist,
                                                    int* __restrict__ base) {
  __shared__ int sp[1024];
  int t = threadIdx.x;
  int h0 = hist[4 * t], h1 = hist[4 * t + 1], h2 = hist[4 * t + 2], h3 = hist[4 * t + 3];
  int s = h0 + h1 + h2 + h3;
  int acc = s;
  sp[t] = s;
  __syncthreads();
  for (int off = 1; off < 1024; off <<= 1) {
    int v = (t >= off) ? sp[t - off] : 0;
    __syncthreads();
    acc += v;
    sp[t] = acc;
    __syncthreads();
  }
  int excl = acc - s;
  base[4 * t + 0] = excl;
  base[4 * t + 1] = excl + h0;
  base[4 * t + 2] = excl + h0 + h1;
  base[4 * t + 3] = excl + h0 + h1 + h2;
}

__global__ void scatter_kernel(const float* __restrict__ pos, const int* __restrict__ cellid,
                               int* __restrict__ base, float* __restrict__ xs,
                               float* __restrict__ ys, float* __restrict__ zs,
                               int* __restrict__ oid) {
  int i = blockIdx.x * 256 + threadIdx.x;
  int c = cellid[i];
  int d = atomicAdd(&base[c], 1);
  xs[d] = pos[3 * i]; ys[d] = pos[3 * i + 1]; zs[d] = pos[3 * i + 2];
  oid[d] = i;
}

// ======================= FPS: R23 (from R22 @ 7.15 ms) ======================
// R22 post-mortem: three tail restructures (R20/21/22) all plateau at
// 2050-2100 cy/iter -> tail not dominant. VALUBusy 0.214 chip = ~55% CU-local
// = ~1150 cy/SIMD/iter issue; ~half is BODY issue (avg ~8 active waves x
// ~140 inst). R23 cuts body issue ~25%:
//  KEY RE-LAYOUT: kj = ((u64)mb << 32) | C  (was (mb>>4)<<32 | mb<<28 | C).
//  - same lex order (md bits, then (16383-oid), then sidx; bits[31:28]=0 pad)
//  - positive-double fmax still valid: mb <= 0x7F7FFFFF (finite float >= 0)
//    -> double exp field = mb[30:20] <= 0x7F7 != 0x7FF, sign 0.
//  - ((u64)mb<<32)|C is a REG_SEQUENCE pair build (no shifts): per-point cost
//    drops from {lshr,lshl_or,max_f64} to {<=1 mov, max_f64}.
//  - cmaxf extract = high word of ckey (free), was a >>28 shift.
// Unchanged from R22: pk body math (exact per-op RNE), prune, 6-stage dpp wave
// reduce, lane63 plain ds_write_b64 publish, parity s_k buffer, 4-stage ror
// block reduce, scalar center loads. Bit-identical output.
#define FPS_T 1024
#define PPT   16

#define PT_LIST(OP) OP(0) OP(1) OP(2) OP(3) OP(4) OP(5) OP(6) OP(7) \
                    OP(8) OP(9) OP(10) OP(11) OP(12) OP(13) OP(14) OP(15)
// OP(G, J0,J1,J2,J3, PA,PB): float4 group G covers points 4G..4G+3, pairs PA=2G, PB=2G+1
#define G4_LIST(OP) OP(0,0,1,2,3,0,1)   OP(1,4,5,6,7,2,3) \
                    OP(2,8,9,10,11,4,5) OP(3,12,13,14,15,6,7)
#define PR_LIST(OP) OP(0) OP(1) OP(2) OP(3) OP(4) OP(5) OP(6) OP(7)

// u64 max via positive-double max (key high word = finite positive float bits
// -> double exponent never all-ones, sign 0; positive doubles order == bit
// order).
__device__ __forceinline__ u64 u64fmax(u64 a, u64 b) {
  double ad = __longlong_as_double((long long)a);
  double bd = __longlong_as_double((long long)b);
  return (u64)(long long)__double_as_longlong(fmax(ad, bd));
}

template <int CTRL, int RM>
__device__ __forceinline__ u64 dppmax(u64 cur) {
  int slo = __builtin_amdgcn_update_dpp(0, (int)(u32)cur, CTRL, RM, 0xf, false);
  int shi = __builtin_amdgcn_update_dpp(0, (int)(u32)(cur >> 32), CTRL, RM, 0xf, false);
  u64 o = ((u64)(u32)shi << 32) | (u32)slo;
  return u64fmax(o, cur);
}

// packed 2xf32 ops (VOP3P, gfx90a+). IEEE RNE per element, no contraction
// possible (opaque asm), denorm mode identical to scalar VALU.
__device__ __forceinline__ f32x2 pk_add(f32x2 a, f32x2 b) {
  f32x2 d;
  asm("v_pk_add_f32 %0, %1, %2" : "=v"(d) : "v"(a), "v"(b));
  return d;
}
__device__ __forceinline__ f32x2 pk_mul(f32x2 a, f32x2 b) {
  f32x2 d;
  asm("v_pk_mul_f32 %0, %1, %2" : "=v"(d) : "v"(a), "v"(b));
  return d;
}

__global__ __launch_bounds__(FPS_T, 4)
void fps_kernel(const float* __restrict__ pos,
                const float* __restrict__ xs,
                const float* __restrict__ ys,
                const float* __restrict__ zs,
                const int* __restrict__ oidv,
                int* __restrict__ idx_out) {
  __shared__ u64 s_k[2][16];                // parity double-buffer of wave keys
  const int t = threadIdx.x;
  const int wv = t >> 6;
  const int base0 = t * PPT;
  const float4* __restrict__ xv = (const float4*)(xs + base0);
  const float4* __restrict__ yv = (const float4*)(ys + base0);
  const float4* __restrict__ zv = (const float4*)(zs + base0);
  const int4*   __restrict__ ov = (const int4*)(oidv + base0);

  // ---- per-point register state: md, x/y/z pairs, key low-word constants
#define DECLP(J) float md##J;
  PT_LIST(DECLP)
#undef DECLP
#define DECLC(J) u32 C##J;
  PT_LIST(DECLC)
#undef DECLC
#define DECLX(P) f32x2 X##P; f32x2 Y##P; f32x2 Z##P;
  PR_LIST(DECLX)
#undef DECLX

  // lane-private chunk bbox lives in registers (constant after init)
  float bnx = 3.4e38f, bxx = -3.4e38f, bny = 3.4e38f, bxy = -3.4e38f,
        bnz = 3.4e38f, bxz = -3.4e38f;

#define INIT4(G, J0, J1, J2, J3, PA, PB) { \
    float4 vx = xv[G], vy = yv[G], vz = zv[G]; int4 vo = ov[G]; \
    md##J0 = 3.402823466e38f; md##J1 = 3.402823466e38f; \
    md##J2 = 3.402823466e38f; md##J3 = 3.402823466e38f; \
    X##PA.x = vx.x; X##PA.y = vx.y; X##PB.x = vx.z; X##PB.y = vx.w; \
    Y##PA.x = vy.x; Y##PA.y = vy.y; Y##PB.x = vy.z; Y##PB.y = vy.w; \
    Z##PA.x = vz.x; Z##PA.y = vz.y; Z##PB.x = vz.z; Z##PB.y = vz.w; \
    C##J0 = ((16383u - (u32)vo.x) << 14) | (u32)(base0 + J0); \
    C##J1 = ((16383u - (u32)vo.y) << 14) | (u32)(base0 + J1); \
    C##J2 = ((16383u - (u32)vo.z) << 14) | (u32)(base0 + J2); \
    C##J3 = ((16383u - (u32)vo.w) << 14) | (u32)(base0 + J3); \
    bnx = fminf(bnx, fminf(fminf(vx.x, vx.y), fminf(vx.z, vx.w))); \
    bxx = fmaxf(bxx, fmaxf(fmaxf(vx.x, vx.y), fmaxf(vx.z, vx.w))); \
    bny = fminf(bny, fminf(fminf(vy.x, vy.y), fminf(vy.z, vy.w))); \
    bxy = fmaxf(bxy, fmaxf(fmaxf(vy.x, vy.y), fmaxf(vy.z, vy.w))); \
    bnz = fminf(bnz, fminf(fminf(vz.x, vz.y), fminf(vz.z, vz.w))); \
    bxz = fmaxf(bxz, fmaxf(fmaxf(vz.x, vz.y), fmaxf(vz.z, vz.w))); }
  G4_LIST(INIT4)
#undef INIT4

  // key = md_bits<<32 | (16383-oid)<<14 | sidx (bits 31:28 zero). md >= 0 ->
  // float order == bit order. Lex max == numpy argmax (max md, tie -> min
  // oid); sidx trails.
  u64 ckey = 0;
  u64 wklast = 0;                       // per-lane dpp partial; lane 63 = wave max
  float cmaxf = 3.402823466e38f;        // forces all-active first iteration
  float cx = pos[0], cy = pos[1], cz = pos[2];
  if (t == 0) idx_out[0] = 0;
  __syncthreads();

  for (int k = 0; k < N_S - 1; ++k) {
    // ---- prune: bbox lower bound vs chunk max-min-dist. Skip-safe: if
    // 0.99*lb2 >= cmaxf no md in this chunk can decrease (1% margin >> fp32
    // rounding of 3-term sums) -> chunk state exactly unchanged.
    float dxl = fmaxf(fmaxf(bnx - cx, cx - bxx), 0.0f);
    float dyl = fmaxf(fmaxf(bny - cy, cy - bxy), 0.0f);
    float dzl = fmaxf(fmaxf(bnz - cz, cz - bxz), 0.0f);
    float lb2 = dxl * dxl + dyl * dyl + dzl * dzl;
    bool act = (0.99f * lb2 < cmaxf);

    if (__ballot(act)) {
      if (act) {
        f32x2 ncx2; ncx2.x = -cx; ncx2.y = -cx;
        f32x2 ncy2; ncy2.x = -cy; ncy2.y = -cy;
        f32x2 ncz2; ncz2.x = -cz; ncz2.y = -cz;
        u64 bkA = 0, bkB = 0;   // even/odd accumulators: halves the dep chain
        // exact numpy arithmetic per element: x+(-c) == x-c (negation exact),
        // pk mul/add are per-op RNE, association (dx2+dy2)+dz2 preserved.
        // Key build is a register-pair: ((u64)md_bits<<32)|C -> no shifts.
#define UPDP(P, J0, J1) { \
        f32x2 dx2 = pk_add(X##P, ncx2); \
        f32x2 dy2 = pk_add(Y##P, ncy2); \
        f32x2 dz2 = pk_add(Z##P, ncz2); \
        f32x2 sq = pk_add(pk_mul(dx2, dx2), pk_mul(dy2, dy2)); \
        f32x2 d2 = pk_add(sq, pk_mul(dz2, dz2)); \
        float m0 = fminf(md##J0, d2.x); md##J0 = m0; \
        bkA = u64fmax(bkA, ((u64)__float_as_uint(m0) << 32) | C##J0); \
        float m1 = fminf(md##J1, d2.y); md##J1 = m1; \
        bkB = u64fmax(bkB, ((u64)__float_as_uint(m1) << 32) | C##J1); }
        UPDP(0, 0, 1)  UPDP(1, 2, 3)  UPDP(2, 4, 5)  UPDP(3, 6, 7)
        UPDP(4, 8, 9)  UPDP(5, 10, 11) UPDP(6, 12, 13) UPDP(7, 14, 15)
#undef UPDP
        ckey = u64fmax(bkA, bkB);
        cmaxf = __uint_as_float((u32)(ckey >> 32));   // high word: free extract
      }
      // wave64 max via DPP (row_shr scan + row broadcasts): lane 63 = wave max.
      // Inactive lanes carry their old (still-valid) ckey.
      u64 wk = ckey;
      wk = dppmax<0x111, 0xf>(wk);   // row_shr:1
      wk = dppmax<0x112, 0xf>(wk);   // row_shr:2
      wk = dppmax<0x114, 0xf>(wk);   // row_shr:4
      wk = dppmax<0x118, 0xf>(wk);   // row_shr:8
      wk = dppmax<0x142, 0xa>(wk);   // row_bcast:15 -> rows 1,3
      wk = dppmax<0x143, 0xc>(wk);   // row_bcast:31 -> rows 2,3
      wklast = wk;                   // lane63's value = wave max
    }
    // publish: single-lane plain write (no RMW). Pruned waves re-publish
    // wklast (exact: their mds unchanged, md monotone non-increasing).
    if ((t & 63) == 63) s_k[k & 1][wv] = wklast;
    __syncthreads();

    // ---- all waves redundantly reduce the 16 wave keys: ONE vector b64 read
    // (16 addrs, 4x replicated broadcast, bank-sweep, conflict-free) + 4-stage
    // row_ror dppmax (period-16) -> every lane holds the global max.
    u64 gk = s_k[k & 1][t & 15];
    gk = dppmax<0x121, 0xf>(gk);   // row_ror:1
    gk = dppmax<0x122, 0xf>(gk);   // row_ror:2
    gk = dppmax<0x124, 0xf>(gk);   // row_ror:4
    gk = dppmax<0x128, 0xf>(gk);   // row_ror:8
    u32 glo = (u32)__builtin_amdgcn_readfirstlane((int)(u32)gk);
    u32 ghi = (u32)__builtin_amdgcn_readfirstlane((int)(u32)(gk >> 32));
    u64 gmax = ((u64)ghi << 32) | glo;
    int sidx = (int)(gmax & 16383u);      // SGPR (from readfirstlane chain)
    if (t == 0) idx_out[k + 1] = 16383 - (int)((gmax >> 14) & 16383u);
    // next center: sidx is uniform -> scalar loads from sorted xs/ys/zs
    // (SMEM/L2 path, 3 parallel, off the LDS pipe).
    cx = xs[sidx];
    cy = ys[sidx];
    cz = zs[sidx];
  }
}

// ======================= zero the tail rows [N_S, N_PTS) =======================
__global__ void zero_tail(float4* __restrict__ outv, int count) {
  int i = blockIdx.x * blockDim.x + threadIdx.x;
  if (i < count) outv[i] = make_float4(0.f, 0.f, 0.f, 0.f);
}

// ======================= kNN: 8-way split + exact lex merge =======================
#define KNN_T  256   // 32 centers x 8 splits
#define KTILE  1024

__global__ __launch_bounds__(KNN_T) void knn_kernel(const float* __restrict__ pos,
                                                    const int* __restrict__ fps_idx,
                                                    int* __restrict__ src_out,
                                                    int* __restrict__ valid_out) {
  __shared__ float sx[KTILE], sy[KTILE], sz[KTILE];
  __shared__ float spd[32][8][NB];
  __shared__ int   spi[32][8][NB];
  const int t = threadIdx.x;
  const int sp = t >> 5;
  const int cl = t & 31;
  const int i = blockIdx.x * 32 + cl;
  const int ci = fps_idx[i];
  const float cx = pos[3 * ci], cy = pos[3 * ci + 1], cz = pos[3 * ci + 2];
  float nd[NB]; int ni[NB];
#pragma unroll
  for (int q = 0; q < NB; ++q) { nd[q] = 3.402823466e38f; ni[q] = 0x7fffffff; }

  for (int base = 0; base < N_PTS; base += KTILE) {
    __syncthreads();
    for (int j = t; j < KTILE; j += KNN_T) {
      int pnt = base + j;
      sx[j] = pos[3 * pnt]; sy[j] = pos[3 * pnt + 1]; sz[j] = pos[3 * pnt + 2];
    }
    __syncthreads();
    for (int j = sp; j < KTILE; j += 8) {
      float dx = __fsub_rn(cx, sx[j]);
      float dy = __fsub_rn(cy, sy[j]);
      float dz = __fsub_rn(cz, sz[j]);
      float d2 = __fadd_rn(__fadd_rn(__fmul_rn(dx, dx), __fmul_rn(dy, dy)), __fmul_rn(dz, dz));
      if (d2 < nd[NB - 1]) {
        float cd = d2; int cp = base + j;
#pragma unroll
        for (int q = 0; q < NB; ++q) {
          bool sw = (cd < nd[q]) || (cd == nd[q] && cp < ni[q]);
          if (sw) { float td = nd[q]; int tp = ni[q]; nd[q] = cd; ni[q] = cp; cd = td; cp = tp; }
        }
      }
    }
  }
#pragma unroll
  for (int q = 0; q < NB; ++q) { spd[cl][sp][q] = nd[q]; spi[cl][sp][q] = ni[q]; }
  __syncthreads();
  if (sp == 0) {
    int cur[8];
#pragma unroll
    for (int s = 0; s < 8; ++s) cur[s] = 0;
    int vb = 0;
    for (int q = 0; q < NB; ++q) {
      float bd = 3.402823466e38f; int bi = 0x7fffffff; int bsl = 0;
#pragma unroll
      for (int s = 0; s < 8; ++s) {
        float d = spd[cl][s][cur[s]]; int id = spi[cl][s][cur[s]];
        if (d < bd || (d == bd && id < bi)) { bd = d; bi = id; bsl = s; }
      }
#pragma unroll
      for (int s = 0; s < 8; ++s) cur[s] += (s == bsl) ? 1 : 0;
      src_out[i * NB + q] = bi;
      if (bd <= R2) vb |= (1 << q);
    }
    valid_out[i] = vb;
  }
}

// ======================= MLP + masked max-pool =======================
#define MLP_T 128

__global__ __launch_bounds__(MLP_T) void mlp_kernel(const float* __restrict__ pos,
                                                    const int* __restrict__ src,
                                                    const int* __restrict__ valid,
                                                    const float* __restrict__ W1,
                                                    const float* __restrict__ b1,
                                                    const float* __restrict__ W2,
                                                    const float* __restrict__ b2,
                                                    float* __restrict__ out) {
  __shared__ float sW2[CHID * COUT];
  __shared__ float sW1[3 * CHID];
  __shared__ float sb1[CHID];
  __shared__ float sh1[NB][CHID];
  __shared__ float srel[NB][3];
  __shared__ int   svalid;
  const int t = threadIdx.x;
  const int i = blockIdx.x;

  for (int e = t; e < CHID * COUT; e += MLP_T) sW2[e] = W2[e];
  for (int e = t; e < 3 * CHID; e += MLP_T) sW1[e] = W1[e];
  if (t < CHID) sb1[t] = b1[t];
  if (t < NB) {
    int s = src[i * NB + t];
    // NOTE: reference subtracts pos_i = pos[:s] (row i), NOT the sampled center
    srel[t][0] = pos[3 * s + 0] - pos[3 * i + 0];
    srel[t][1] = pos[3 * s + 1] - pos[3 * i + 1];
    srel[t][2] = pos[3 * s + 2] - pos[3 * i + 2];
  }
  if (t == 0) svalid = valid[i];
  __syncthreads();

  for (int e = t; e < NB * CHID; e += MLP_T) {
    int n = e >> 6, kk = e & 63;
    float a = sb1[kk] + srel[n][0] * sW1[kk] + srel[n][1] * sW1[64 + kk] + srel[n][2] * sW1[128 + kk];
    sh1[n][kk] = fmaxf(a, 0.0f);
  }
  __syncthreads();

  const int vmask = svalid;
  const float bb = b2[t];
  float m = 0.0f;
  bool any = false;
  for (int n = 0; n < NB; ++n) {
    if (vmask & (1 << n)) {
      float acc = bb;
      for (int kk = 0; kk < CHID; ++kk) acc += sh1[n][kk] * sW2[kk * COUT + t];
      m = any ? fmaxf(m, acc) : acc;
      any = true;
    }
  }
  out[i * COUT + t] = any ? m : 0.0f;
}

// ======================= launch =======================
extern "C" void kernel_launch(void* const* d_in, const int* in_sizes, int n_in,
                              void* d_out, int out_size, void* d_ws, size_t ws_size,
                              hipStream_t stream) {
  (void)in_sizes; (void)n_in; (void)out_size; (void)ws_size;
  const float* pos = (const float*)d_in[0];
  const float* W1 = (const float*)d_in[2];
  const float* b1 = (const float*)d_in[3];
  const float* W2 = (const float*)d_in[4];
  const float* b2 = (const float*)d_in[5];
  float* out = (float*)d_out;

  char* ws = (char*)d_ws;
  int*   idx   = (int*)ws;                 ws += (size_t)N_S * 4;          // 32 KB
  int*   src   = (int*)ws;                 ws += (size_t)N_S * NB * 4;     // 320 KB
  int*   valid = (int*)ws;                 ws += (size_t)N_S * 4;          // 32 KB
  float* xs    = (float*)ws;               ws += (size_t)N_PTS * 4;        // 64 KB
  float* ys    = (float*)ws;               ws += (size_t)N_PTS * 4;
  float* zs    = (float*)ws;               ws += (size_t)N_PTS * 4;
  int*   oid   = (int*)ws;                 ws += (size_t)N_PTS * 4;
  // sort temporaries alias the src region (sort completes before knn writes src)
  int* cellid = src;                 // N_PTS ints = 64 KB  (src region is 320 KB)
  int* hist   = src + N_PTS;         // NCELL ints = 16 KB
  int* basebuf= src + N_PTS + NCELL; // NCELL ints = 16 KB

  zero_hist<<<NCELL / 256, 256, 0, stream>>>(hist);
  cell_kernel<<<N_PTS / 256, 256, 0, stream>>>(pos, cellid, hist);
  scan_kernel<<<1, 1024, 0, stream>>>(hist, basebuf);
  scatter_kernel<<<N_PTS / 256, 256, 0, stream>>>(pos, cellid, basebuf, xs, ys, zs, oid);
  fps_kernel<<<1, FPS_T, 0, stream>>>(pos, xs, ys, zs, oid, idx);
  {
    int count = (N_PTS - N_S) * COUT / 4;
    zero_tail<<<(count + 255) / 256, 256, 0, stream>>>((float4*)(out + (size_t)N_S * COUT), count);
  }
  knn_kernel<<<N_S / 32, KNN_T, 0, stream>>>(pos, idx, src, valid);
  mlp_kernel<<<N_S, MLP_T, 0, stream>>>(pos, src, valid, W1, b1, W2, b2, out);
}

// Round 8
// 7427.393 us; speedup vs baseline: 1.1628x; 1.0276x over previous
//
#include <hip/hip_runtime.h>

typedef unsigned int u32;
typedef unsigned long long u64;
typedef float f32x2 __attribute__((ext_vector_type(2)));

#define N_PTS 16384
#define N_S   8192
#define NB    10
#define CHID  64
#define COUT  128
#define R2    0.0625f
#define NCELL 4096

// ======================= sort: morton counting sort =======================
__global__ void zero_hist(int* __restrict__ hist) {
  hist[blockIdx.x * 256 + threadIdx.x] = 0;
}

__device__ __forceinline__ u32 spread3(u32 v) {  // 4 bits -> every 3rd bit
  return (v & 1u) | ((v & 2u) << 2) | ((v & 4u) << 4) | ((v & 8u) << 6);
}

__global__ void cell_kernel(const float* __restrict__ pos, int* __restrict__ cellid,
                            int* __restrict__ hist) {
  int i = blockIdx.x * 256 + threadIdx.x;
  float x = pos[3 * i], y = pos[3 * i + 1], z = pos[3 * i + 2];
  u32 ix = (u32)(x * 16.0f); if (ix > 15u) ix = 15u;
  u32 iy = (u32)(y * 16.0f); if (iy > 15u) iy = 15u;
  u32 iz = (u32)(z * 16.0f); if (iz > 15u) iz = 15u;
  u32 c = spread3(ix) | (spread3(iy) << 1) | (spread3(iz) << 2);
  cellid[i] = (int)c;
  atomicAdd(&hist[c], 1);
}

__global__ __launch_bounds__(1024) void scan_kernel(const int* __restrict__ hist,
                                                    int* __restrict__ base) {
  __shared__ int sp[1024];
  int t = threadIdx.x;
  int h0 = hist[4 * t], h1 = hist[4 * t + 1], h2 = hist[4 * t + 2], h3 = hist[4 * t + 3];
  int s = h0 + h1 + h2 + h3;
  int acc = s;
  sp[t] = s;
  __syncthreads();
  for (int off = 1; off < 1024; off <<= 1) {
    int v = (t >= off) ? sp[t - off] : 0;
    __syncthreads();
    acc += v;
    sp[t] = acc;
    __syncthreads();
  }
  int excl = acc - s;
  base[4 * t + 0] = excl;
  base[4 * t + 1] = excl + h0;
  base[4 * t + 2] = excl + h0 + h1;
  base[4 * t + 3] = excl + h0 + h1 + h2;
}

__global__ void scatter_kernel(const float* __restrict__ pos, const int* __restrict__ cellid,
                               int* __restrict__ base, float* __restrict__ xs,
                               float* __restrict__ ys, float* __restrict__ zs,
                               int* __restrict__ oid) {
  int i = blockIdx.x * 256 + threadIdx.x;
  int c = cellid[i];
  int d = atomicAdd(&base[c], 1);
  xs[d] = pos[3 * i]; ys[d] = pos[3 * i + 1]; zs[d] = pos[3 * i + 2];
  oid[d] = i;
}

// ======================= FPS: R24 (from R23 @ 6.87 ms) ======================
// R23 post-mortem: key relayout matched (-82 cy/iter). R24 isolates R22's
// hidden regression: center cy/cz moved from s_yz LDS b64 (~120 cy) to scalar
// loads (~250-300 cy, scalar-cache miss each iter) -- that fetch is on the
// post-barrier critical chain (everything depends on gmax -> c). Reinstate
// s_yz (128 KB, written once) for cy/cz; cx stays on the vector/global path
// (overlaps the LDS read). Chain: ds_read(120)+dpp(50)+rfl(10)+max(120,180)
// ~= 360 cy vs R23's ~430.
// Everything else identical to R23: pair-build key ((u64)md<<32|C), pk body,
// prune, 6-stage dpp wave reduce, lane63 plain publish, parity s_k, 4-stage
// ror block reduce. Bit-identical output.
#define FPS_T 1024
#define PPT   16

#define PT_LIST(OP) OP(0) OP(1) OP(2) OP(3) OP(4) OP(5) OP(6) OP(7) \
                    OP(8) OP(9) OP(10) OP(11) OP(12) OP(13) OP(14) OP(15)
// OP(G, J0,J1,J2,J3, PA,PB): float4 group G covers points 4G..4G+3, pairs PA=2G, PB=2G+1
#define G4_LIST(OP) OP(0,0,1,2,3,0,1)   OP(1,4,5,6,7,2,3) \
                    OP(2,8,9,10,11,4,5) OP(3,12,13,14,15,6,7)
#define PR_LIST(OP) OP(0) OP(1) OP(2) OP(3) OP(4) OP(5) OP(6) OP(7)

// u64 max via positive-double max (key high word = finite positive float bits
// -> double exponent never all-ones, sign 0; positive doubles order == bit
// order).
__device__ __forceinline__ u64 u64fmax(u64 a, u64 b) {
  double ad = __longlong_as_double((long long)a);
  double bd = __longlong_as_double((long long)b);
  return (u64)(long long)__double_as_longlong(fmax(ad, bd));
}

template <int CTRL, int RM>
__device__ __forceinline__ u64 dppmax(u64 cur) {
  int slo = __builtin_amdgcn_update_dpp(0, (int)(u32)cur, CTRL, RM, 0xf, false);
  int shi = __builtin_amdgcn_update_dpp(0, (int)(u32)(cur >> 32), CTRL, RM, 0xf, false);
  u64 o = ((u64)(u32)shi << 32) | (u32)slo;
  return u64fmax(o, cur);
}

// packed 2xf32 ops (VOP3P, gfx90a+). IEEE RNE per element, no contraction
// possible (opaque asm), denorm mode identical to scalar VALU.
__device__ __forceinline__ f32x2 pk_add(f32x2 a, f32x2 b) {
  f32x2 d;
  asm("v_pk_add_f32 %0, %1, %2" : "=v"(d) : "v"(a), "v"(b));
  return d;
}
__device__ __forceinline__ f32x2 pk_mul(f32x2 a, f32x2 b) {
  f32x2 d;
  asm("v_pk_mul_f32 %0, %1, %2" : "=v"(d) : "v"(a), "v"(b));
  return d;
}

__global__ __launch_bounds__(FPS_T, 4)
void fps_kernel(const float* __restrict__ pos,
                const float* __restrict__ xs,
                const float* __restrict__ ys,
                const float* __restrict__ zs,
                const int* __restrict__ oidv,
                int* __restrict__ idx_out) {
  __shared__ float2 s_yz[PPT * FPS_T];      // [j][t] (y,z): 128 KB (center fetch only)
  __shared__ u64 s_k[2][16];                // parity double-buffer of wave keys
  const int t = threadIdx.x;
  const int wv = t >> 6;
  const int base0 = t * PPT;
  const float4* __restrict__ xv = (const float4*)(xs + base0);
  const float4* __restrict__ yv = (const float4*)(ys + base0);
  const float4* __restrict__ zv = (const float4*)(zs + base0);
  const int4*   __restrict__ ov = (const int4*)(oidv + base0);

  // ---- per-point register state: md, x/y/z pairs, key low-word constants
#define DECLP(J) float md##J;
  PT_LIST(DECLP)
#undef DECLP
#define DECLC(J) u32 C##J;
  PT_LIST(DECLC)
#undef DECLC
#define DECLX(P) f32x2 X##P; f32x2 Y##P; f32x2 Z##P;
  PR_LIST(DECLX)
#undef DECLX

  // lane-private chunk bbox lives in registers (constant after init)
  float bnx = 3.4e38f, bxx = -3.4e38f, bny = 3.4e38f, bxy = -3.4e38f,
        bnz = 3.4e38f, bxz = -3.4e38f;

#define INIT4(G, J0, J1, J2, J3, PA, PB) { \
    float4 vx = xv[G], vy = yv[G], vz = zv[G]; int4 vo = ov[G]; \
    md##J0 = 3.402823466e38f; md##J1 = 3.402823466e38f; \
    md##J2 = 3.402823466e38f; md##J3 = 3.402823466e38f; \
    X##PA.x = vx.x; X##PA.y = vx.y; X##PB.x = vx.z; X##PB.y = vx.w; \
    Y##PA.x = vy.x; Y##PA.y = vy.y; Y##PB.x = vy.z; Y##PB.y = vy.w; \
    Z##PA.x = vz.x; Z##PA.y = vz.y; Z##PB.x = vz.z; Z##PB.y = vz.w; \
    s_yz[J0 * FPS_T + t] = make_float2(vy.x, vz.x); \
    s_yz[J1 * FPS_T + t] = make_float2(vy.y, vz.y); \
    s_yz[J2 * FPS_T + t] = make_float2(vy.z, vz.z); \
    s_yz[J3 * FPS_T + t] = make_float2(vy.w, vz.w); \
    C##J0 = ((16383u - (u32)vo.x) << 14) | (u32)(base0 + J0); \
    C##J1 = ((16383u - (u32)vo.y) << 14) | (u32)(base0 + J1); \
    C##J2 = ((16383u - (u32)vo.z) << 14) | (u32)(base0 + J2); \
    C##J3 = ((16383u - (u32)vo.w) << 14) | (u32)(base0 + J3); \
    bnx = fminf(bnx, fminf(fminf(vx.x, vx.y), fminf(vx.z, vx.w))); \
    bxx = fmaxf(bxx, fmaxf(fmaxf(vx.x, vx.y), fmaxf(vx.z, vx.w))); \
    bny = fminf(bny, fminf(fminf(vy.x, vy.y), fminf(vy.z, vy.w))); \
    bxy = fmaxf(bxy, fmaxf(fmaxf(vy.x, vy.y), fmaxf(vy.z, vy.w))); \
    bnz = fminf(bnz, fminf(fminf(vz.x, vz.y), fminf(vz.z, vz.w))); \
    bxz = fmaxf(bxz, fmaxf(fmaxf(vz.x, vz.y), fmaxf(vz.z, vz.w))); }
  G4_LIST(INIT4)
#undef INIT4

  // key = md_bits<<32 | (16383-oid)<<14 | sidx (bits 31:28 zero). md >= 0 ->
  // float order == bit order. Lex max == numpy argmax (max md, tie -> min
  // oid); sidx trails.
  u64 ckey = 0;
  u64 wklast = 0;                       // per-lane dpp partial; lane 63 = wave max
  float cmaxf = 3.402823466e38f;        // forces all-active first iteration
  float cx = pos[0], cy = pos[1], cz = pos[2];
  if (t == 0) idx_out[0] = 0;
  __syncthreads();

  for (int k = 0; k < N_S - 1; ++k) {
    // ---- prune: bbox lower bound vs chunk max-min-dist. Skip-safe: if
    // 0.99*lb2 >= cmaxf no md in this chunk can decrease (1% margin >> fp32
    // rounding of 3-term sums) -> chunk state exactly unchanged.
    float dxl = fmaxf(fmaxf(bnx - cx, cx - bxx), 0.0f);
    float dyl = fmaxf(fmaxf(bny - cy, cy - bxy), 0.0f);
    float dzl = fmaxf(fmaxf(bnz - cz, cz - bxz), 0.0f);
    float lb2 = dxl * dxl + dyl * dyl + dzl * dzl;
    bool act = (0.99f * lb2 < cmaxf);

    if (__ballot(act)) {
      if (act) {
        f32x2 ncx2; ncx2.x = -cx; ncx2.y = -cx;
        f32x2 ncy2; ncy2.x = -cy; ncy2.y = -cy;
        f32x2 ncz2; ncz2.x = -cz; ncz2.y = -cz;
        u64 bkA = 0, bkB = 0;   // even/odd accumulators: halves the dep chain
        // exact numpy arithmetic per element: x+(-c) == x-c (negation exact),
        // pk mul/add are per-op RNE, association (dx2+dy2)+dz2 preserved.
        // Key build is a register-pair: ((u64)md_bits<<32)|C -> no shifts.
#define UPDP(P, J0, J1) { \
        f32x2 dx2 = pk_add(X##P, ncx2); \
        f32x2 dy2 = pk_add(Y##P, ncy2); \
        f32x2 dz2 = pk_add(Z##P, ncz2); \
        f32x2 sq = pk_add(pk_mul(dx2, dx2), pk_mul(dy2, dy2)); \
        f32x2 d2 = pk_add(sq, pk_mul(dz2, dz2)); \
        float m0 = fminf(md##J0, d2.x); md##J0 = m0; \
        bkA = u64fmax(bkA, ((u64)__float_as_uint(m0) << 32) | C##J0); \
        float m1 = fminf(md##J1, d2.y); md##J1 = m1; \
        bkB = u64fmax(bkB, ((u64)__float_as_uint(m1) << 32) | C##J1); }
        UPDP(0, 0, 1)  UPDP(1, 2, 3)  UPDP(2, 4, 5)  UPDP(3, 6, 7)
        UPDP(4, 8, 9)  UPDP(5, 10, 11) UPDP(6, 12, 13) UPDP(7, 14, 15)
#undef UPDP
        ckey = u64fmax(bkA, bkB);
        cmaxf = __uint_as_float((u32)(ckey >> 32));   // high word: free extract
      }
      // wave64 max via DPP (row_shr scan + row broadcasts): lane 63 = wave max.
      // Inactive lanes carry their old (still-valid) ckey.
      u64 wk = ckey;
      wk = dppmax<0x111, 0xf>(wk);   // row_shr:1
      wk = dppmax<0x112, 0xf>(wk);   // row_shr:2
      wk = dppmax<0x114, 0xf>(wk);   // row_shr:4
      wk = dppmax<0x118, 0xf>(wk);   // row_shr:8
      wk = dppmax<0x142, 0xa>(wk);   // row_bcast:15 -> rows 1,3
      wk = dppmax<0x143, 0xc>(wk);   // row_bcast:31 -> rows 2,3
      wklast = wk;                   // lane63's value = wave max
    }
    // publish: single-lane plain write (no RMW). Pruned waves re-publish
    // wklast (exact: their mds unchanged, md monotone non-increasing).
    if ((t & 63) == 63) s_k[k & 1][wv] = wklast;
    __syncthreads();

    // ---- all waves redundantly reduce the 16 wave keys: ONE vector b64 read
    // (16 addrs, 4x replicated broadcast, bank-sweep, conflict-free) + 4-stage
    // row_ror dppmax (period-16) -> every lane holds the global max.
    u64 gk = s_k[k & 1][t & 15];
    gk = dppmax<0x121, 0xf>(gk);   // row_ror:1
    gk = dppmax<0x122, 0xf>(gk);   // row_ror:2
    gk = dppmax<0x124, 0xf>(gk);   // row_ror:4
    gk = dppmax<0x128, 0xf>(gk);   // row_ror:8
    u32 glo = (u32)__builtin_amdgcn_readfirstlane((int)(u32)gk);
    u32 ghi = (u32)__builtin_amdgcn_readfirstlane((int)(u32)(gk >> 32));
    u64 gmax = ((u64)ghi << 32) | glo;
    int sidx = (int)(gmax & 16383u);      // SGPR (from readfirstlane chain)
    if (t == 0) idx_out[k + 1] = 16383 - (int)((gmax >> 14) & 16383u);
    // next center: cx via global load from L1/L2-resident xs (overlaps LDS);
    // cy,cz via ONE uniform broadcast b64 read from the point's LDS cell.
    int cell = (sidx & (PPT - 1)) * FPS_T + (sidx >> 4);
    cx = xs[sidx];
    float2 yz = s_yz[cell];
    cy = yz.x;
    cz = yz.y;
  }
}

// ======================= zero the tail rows [N_S, N_PTS) =======================
__global__ void zero_tail(float4* __restrict__ outv, int count) {
  int i = blockIdx.x * blockDim.x + threadIdx.x;
  if (i < count) outv[i] = make_float4(0.f, 0.f, 0.f, 0.f);
}

// ======================= kNN: 16-way split + exact lex merge =======================
// R24: was 8 splits / 256 thr (1 wave/SIMD, zero latency hiding) with
// spd[32][8][NB] lane-stride 80 words == 16 mod 32 -> 16-way bank conflicts
// (SQ_LDS_BANK_CONFLICT 693K). Now: 16 splits / 512 thr (2 waves/SIMD, half
// the per-thread work) + merge arrays padded to stride 161 words (==1 mod 32,
// conflict-free). Exactness: global top-10 of a center is contained in the
// union of its 16 per-split top-10s; merge takes lex-min (d, idx) repeatedly
// -- identical semantics to the 8-way version.
#define KNN_T  512   // 32 centers x 16 splits
#define KNS    16
#define KTILE  1024
#define KPAD   161   // KNS*NB=160 -> pad to 161 (odd, ==1 mod 32)

__global__ __launch_bounds__(KNN_T) void knn_kernel(const float* __restrict__ pos,
                                                    const int* __restrict__ fps_idx,
                                                    int* __restrict__ src_out,
                                                    int* __restrict__ valid_out) {
  __shared__ float sx[KTILE], sy[KTILE], sz[KTILE];
  __shared__ float spd[32][KPAD];
  __shared__ int   spi[32][KPAD];
  const int t = threadIdx.x;
  const int sp = t >> 5;          // split 0..15
  const int cl = t & 31;          // center lane 0..31
  const int i = blockIdx.x * 32 + cl;
  const int ci = fps_idx[i];
  const float cx = pos[3 * ci], cy = pos[3 * ci + 1], cz = pos[3 * ci + 2];
  float nd[NB]; int ni[NB];
#pragma unroll
  for (int q = 0; q < NB; ++q) { nd[q] = 3.402823466e38f; ni[q] = 0x7fffffff; }

  for (int base = 0; base < N_PTS; base += KTILE) {
    __syncthreads();
    for (int j = t; j < KTILE; j += KNN_T) {
      int pnt = base + j;
      sx[j] = pos[3 * pnt]; sy[j] = pos[3 * pnt + 1]; sz[j] = pos[3 * pnt + 2];
    }
    __syncthreads();
    for (int j = sp; j < KTILE; j += KNS) {
      float dx = __fsub_rn(cx, sx[j]);
      float dy = __fsub_rn(cy, sy[j]);
      float dz = __fsub_rn(cz, sz[j]);
      float d2 = __fadd_rn(__fadd_rn(__fmul_rn(dx, dx), __fmul_rn(dy, dy)), __fmul_rn(dz, dz));
      if (d2 < nd[NB - 1]) {
        float cd = d2; int cp = base + j;
#pragma unroll
        for (int q = 0; q < NB; ++q) {
          bool sw = (cd < nd[q]) || (cd == nd[q] && cp < ni[q]);
          if (sw) { float td = nd[q]; int tp = ni[q]; nd[q] = cd; ni[q] = cp; cd = td; cp = tp; }
        }
      }
    }
  }
#pragma unroll
  for (int q = 0; q < NB; ++q) { spd[cl][sp * NB + q] = nd[q]; spi[cl][sp * NB + q] = ni[q]; }
  __syncthreads();
  if (sp == 0) {
    int cur[KNS];
#pragma unroll
    for (int s = 0; s < KNS; ++s) cur[s] = 0;
    int vb = 0;
    for (int q = 0; q < NB; ++q) {
      float bd = 3.402823466e38f; int bi = 0x7fffffff; int bsl = 0;
#pragma unroll
      for (int s = 0; s < KNS; ++s) {
        float d = spd[cl][s * NB + cur[s]]; int id = spi[cl][s * NB + cur[s]];
        if (d < bd || (d == bd && id < bi)) { bd = d; bi = id; bsl = s; }
      }
#pragma unroll
      for (int s = 0; s < KNS; ++s) cur[s] += (s == bsl) ? 1 : 0;
      src_out[i * NB + q] = bi;
      if (bd <= R2) vb |= (1 << q);
    }
    valid_out[i] = vb;
  }
}

// ======================= MLP + masked max-pool =======================
#define MLP_T 128

__global__ __launch_bounds__(MLP_T) void mlp_kernel(const float* __restrict__ pos,
                                                    const int* __restrict__ src,
                                                    const int* __restrict__ valid,
                                                    const float* __restrict__ W1,
                                                    const float* __restrict__ b1,
                                                    const float* __restrict__ W2,
                                                    const float* __restrict__ b2,
                                                    float* __restrict__ out) {
  __shared__ float sW2[CHID * COUT];
  __shared__ float sW1[3 * CHID];
  __shared__ float sb1[CHID];
  __shared__ float sh1[NB][CHID];
  __shared__ float srel[NB][3];
  __shared__ int   svalid;
  const int t = threadIdx.x;
  const int i = blockIdx.x;

  for (int e = t; e < CHID * COUT; e += MLP_T) sW2[e] = W2[e];
  for (int e = t; e < 3 * CHID; e += MLP_T) sW1[e] = W1[e];
  if (t < CHID) sb1[t] = b1[t];
  if (t < NB) {
    int s = src[i * NB + t];
    // NOTE: reference subtracts pos_i = pos[:s] (row i), NOT the sampled center
    srel[t][0] = pos[3 * s + 0] - pos[3 * i + 0];
    srel[t][1] = pos[3 * s + 1] - pos[3 * i + 1];
    srel[t][2] = pos[3 * s + 2] - pos[3 * i + 2];
  }
  if (t == 0) svalid = valid[i];
  __syncthreads();

  for (int e = t; e < NB * CHID; e += MLP_T) {
    int n = e >> 6, kk = e & 63;
    float a = sb1[kk] + srel[n][0] * sW1[kk] + srel[n][1] * sW1[64 + kk] + srel[n][2] * sW1[128 + kk];
    sh1[n][kk] = fmaxf(a, 0.0f);
  }
  __syncthreads();

  const int vmask = svalid;
  const float bb = b2[t];
  float m = 0.0f;
  bool any = false;
  for (int n = 0; n < NB; ++n) {
    if (vmask & (1 << n)) {
      float acc = bb;
      for (int kk = 0; kk < CHID; ++kk) acc += sh1[n][kk] * sW2[kk * COUT + t];
      m = any ? fmaxf(m, acc) : acc;
      any = true;
    }
  }
  out[i * COUT + t] = any ? m : 0.0f;
}

// ======================= launch =======================
extern "C" void kernel_launch(void* const* d_in, const int* in_sizes, int n_in,
                              void* d_out, int out_size, void* d_ws, size_t ws_size,
                              hipStream_t stream) {
  (void)in_sizes; (void)n_in; (void)out_size; (void)ws_size;
  const float* pos = (const float*)d_in[0];
  const float* W1 = (const float*)d_in[2];
  const float* b1 = (const float*)d_in[3];
  const float* W2 = (const float*)d_in[4];
  const float* b2 = (const float*)d_in[5];
  float* out = (float*)d_out;

  char* ws = (char*)d_ws;
  int*   idx   = (int*)ws;                 ws += (size_t)N_S * 4;          // 32 KB
  int*   src   = (int*)ws;                 ws += (size_t)N_S * NB * 4;     // 320 KB
  int*   valid = (int*)ws;                 ws += (size_t)N_S * 4;          // 32 KB
  float* xs    = (float*)ws;               ws += (size_t)N_PTS * 4;        // 64 KB
  float* ys    = (float*)ws;               ws += (size_t)N_PTS * 4;
  float* zs    = (float*)ws;               ws += (size_t)N_PTS * 4;
  int*   oid   = (int*)ws;                 ws += (size_t)N_PTS * 4;
  // sort temporaries alias the src region (sort completes before knn writes src)
  int* cellid = src;                 // N_PTS ints = 64 KB  (src region is 320 KB)
  int* hist   = src + N_PTS;         // NCELL ints = 16 KB
  int* basebuf= src + N_PTS + NCELL; // NCELL ints = 16 KB

  zero_hist<<<NCELL / 256, 256, 0, stream>>>(hist);
  cell_kernel<<<N_PTS / 256, 256, 0, stream>>>(pos, cellid, hist);
  scan_kernel<<<1, 1024, 0, stream>>>(hist, basebuf);
  scatter_kernel<<<N_PTS / 256, 256, 0, stream>>>(pos, cellid, basebuf, xs, ys, zs, oid);
  fps_kernel<<<1, FPS_T, 0, stream>>>(pos, xs, ys, zs, oid, idx);
  {
    int count = (N_PTS - N_S) * COUT / 4;
    zero_tail<<<(count + 255) / 256, 256, 0, stream>>>((float4*)(out + (size_t)N_S * COUT), count);
  }
  knn_kernel<<<N_S / 32, KNN_T, 0, stream>>>(pos, idx, src, valid);
  mlp_kernel<<<N_S, MLP_T, 0, stream>>>(pos, src, valid, W1, b1, W2, b2, out);
}

// Round 9
// 7242.710 us; speedup vs baseline: 1.1925x; 1.0255x over previous
//
#include <hip/hip_runtime.h>

typedef unsigned int u32;
typedef unsigned long long u64;
typedef float f32x2 __attribute__((ext_vector_type(2)));

#define N_PTS 16384
#define N_S   8192
#define NB    10
#define CHID  64
#define COUT  128
#define R2    0.0625f
#define NCELL 4096

// ======================= sort: morton counting sort =======================
__global__ void zero_hist(int* __restrict__ hist) {
  hist[blockIdx.x * 256 + threadIdx.x] = 0;
}

__device__ __forceinline__ u32 spread3(u32 v) {  // 4 bits -> every 3rd bit
  return (v & 1u) | ((v & 2u) << 2) | ((v & 4u) << 4) | ((v & 8u) << 6);
}

__global__ void cell_kernel(const float* __restrict__ pos, int* __restrict__ cellid,
                            int* __restrict__ hist) {
  int i = blockIdx.x * 256 + threadIdx.x;
  float x = pos[3 * i], y = pos[3 * i + 1], z = pos[3 * i + 2];
  u32 ix = (u32)(x * 16.0f); if (ix > 15u) ix = 15u;
  u32 iy = (u32)(y * 16.0f); if (iy > 15u) iy = 15u;
  u32 iz = (u32)(z * 16.0f); if (iz > 15u) iz = 15u;
  u32 c = spread3(ix) | (spread3(iy) << 1) | (spread3(iz) << 2);
  cellid[i] = (int)c;
  atomicAdd(&hist[c], 1);
}

__global__ __launch_bounds__(1024) void scan_kernel(const int* __restrict__ hist,
                                                    int* __restrict__ base) {
  __shared__ int sp[1024];
  int t = threadIdx.x;
  int h0 = hist[4 * t], h1 = hist[4 * t + 1], h2 = hist[4 * t + 2], h3 = hist[4 * t + 3];
  int s = h0 + h1 + h2 + h3;
  int acc = s;
  sp[t] = s;
  __syncthreads();
  for (int off = 1; off < 1024; off <<= 1) {
    int v = (t >= off) ? sp[t - off] : 0;
    __syncthreads();
    acc += v;
    sp[t] = acc;
    __syncthreads();
  }
  int excl = acc - s;
  base[4 * t + 0] = excl;
  base[4 * t + 1] = excl + h0;
  base[4 * t + 2] = excl + h0 + h1;
  base[4 * t + 3] = excl + h0 + h1 + h2;
}

__global__ void scatter_kernel(const float* __restrict__ pos, const int* __restrict__ cellid,
                               int* __restrict__ base, float* __restrict__ xs,
                               float* __restrict__ ys, float* __restrict__ zs,
                               int* __restrict__ oid) {
  int i = blockIdx.x * 256 + threadIdx.x;
  int c = cellid[i];
  int d = atomicAdd(&base[c], 1);
  xs[d] = pos[3 * i]; ys[d] = pos[3 * i + 1]; zs[d] = pos[3 * i + 2];
  oid[d] = i;
}

// ======================= FPS: R24 frozen (6.59 ms verified) ==================
// R24 post-mortem: center fetch back on LDS leg -> -82 cy/iter, matched.
// R25 audit: 1931 cy/iter = ~1200 issue/SIMD (62% CU VALUBusy) + ~500 lockstep
// chain. Body is minimal under exactness (no FMA allowed: md perturbation
// flips argmax -> index changes are catastrophic). 6-stage dpp = minimal
// 64-lane reduce. b128 block-reduce read would ADD 64 lockstep beats to save
// one dpp stage (R21 lesson) -> rejected. FPS UNCHANGED this round.
#define FPS_T 1024
#define PPT   16

#define PT_LIST(OP) OP(0) OP(1) OP(2) OP(3) OP(4) OP(5) OP(6) OP(7) \
                    OP(8) OP(9) OP(10) OP(11) OP(12) OP(13) OP(14) OP(15)
// OP(G, J0,J1,J2,J3, PA,PB): float4 group G covers points 4G..4G+3, pairs PA=2G, PB=2G+1
#define G4_LIST(OP) OP(0,0,1,2,3,0,1)   OP(1,4,5,6,7,2,3) \
                    OP(2,8,9,10,11,4,5) OP(3,12,13,14,15,6,7)
#define PR_LIST(OP) OP(0) OP(1) OP(2) OP(3) OP(4) OP(5) OP(6) OP(7)

// u64 max via positive-double max (key high word = finite positive float bits
// -> double exponent never all-ones, sign 0; positive doubles order == bit
// order).
__device__ __forceinline__ u64 u64fmax(u64 a, u64 b) {
  double ad = __longlong_as_double((long long)a);
  double bd = __longlong_as_double((long long)b);
  return (u64)(long long)__double_as_longlong(fmax(ad, bd));
}

template <int CTRL, int RM>
__device__ __forceinline__ u64 dppmax(u64 cur) {
  int slo = __builtin_amdgcn_update_dpp(0, (int)(u32)cur, CTRL, RM, 0xf, false);
  int shi = __builtin_amdgcn_update_dpp(0, (int)(u32)(cur >> 32), CTRL, RM, 0xf, false);
  u64 o = ((u64)(u32)shi << 32) | (u32)slo;
  return u64fmax(o, cur);
}

// packed 2xf32 ops (VOP3P, gfx90a+). IEEE RNE per element, no contraction
// possible (opaque asm), denorm mode identical to scalar VALU.
__device__ __forceinline__ f32x2 pk_add(f32x2 a, f32x2 b) {
  f32x2 d;
  asm("v_pk_add_f32 %0, %1, %2" : "=v"(d) : "v"(a), "v"(b));
  return d;
}
__device__ __forceinline__ f32x2 pk_mul(f32x2 a, f32x2 b) {
  f32x2 d;
  asm("v_pk_mul_f32 %0, %1, %2" : "=v"(d) : "v"(a), "v"(b));
  return d;
}

__global__ __launch_bounds__(FPS_T, 4)
void fps_kernel(const float* __restrict__ pos,
                const float* __restrict__ xs,
                const float* __restrict__ ys,
                const float* __restrict__ zs,
                const int* __restrict__ oidv,
                int* __restrict__ idx_out) {
  __shared__ float2 s_yz[PPT * FPS_T];      // [j][t] (y,z): 128 KB (center fetch only)
  __shared__ u64 s_k[2][16];                // parity double-buffer of wave keys
  const int t = threadIdx.x;
  const int wv = t >> 6;
  const int base0 = t * PPT;
  const float4* __restrict__ xv = (const float4*)(xs + base0);
  const float4* __restrict__ yv = (const float4*)(ys + base0);
  const float4* __restrict__ zv = (const float4*)(zs + base0);
  const int4*   __restrict__ ov = (const int4*)(oidv + base0);

  // ---- per-point register state: md, x/y/z pairs, key low-word constants
#define DECLP(J) float md##J;
  PT_LIST(DECLP)
#undef DECLP
#define DECLC(J) u32 C##J;
  PT_LIST(DECLC)
#undef DECLC
#define DECLX(P) f32x2 X##P; f32x2 Y##P; f32x2 Z##P;
  PR_LIST(DECLX)
#undef DECLX

  // lane-private chunk bbox lives in registers (constant after init)
  float bnx = 3.4e38f, bxx = -3.4e38f, bny = 3.4e38f, bxy = -3.4e38f,
        bnz = 3.4e38f, bxz = -3.4e38f;

#define INIT4(G, J0, J1, J2, J3, PA, PB) { \
    float4 vx = xv[G], vy = yv[G], vz = zv[G]; int4 vo = ov[G]; \
    md##J0 = 3.402823466e38f; md##J1 = 3.402823466e38f; \
    md##J2 = 3.402823466e38f; md##J3 = 3.402823466e38f; \
    X##PA.x = vx.x; X##PA.y = vx.y; X##PB.x = vx.z; X##PB.y = vx.w; \
    Y##PA.x = vy.x; Y##PA.y = vy.y; Y##PB.x = vy.z; Y##PB.y = vy.w; \
    Z##PA.x = vz.x; Z##PA.y = vz.y; Z##PB.x = vz.z; Z##PB.y = vz.w; \
    s_yz[J0 * FPS_T + t] = make_float2(vy.x, vz.x); \
    s_yz[J1 * FPS_T + t] = make_float2(vy.y, vz.y); \
    s_yz[J2 * FPS_T + t] = make_float2(vy.z, vz.z); \
    s_yz[J3 * FPS_T + t] = make_float2(vy.w, vz.w); \
    C##J0 = ((16383u - (u32)vo.x) << 14) | (u32)(base0 + J0); \
    C##J1 = ((16383u - (u32)vo.y) << 14) | (u32)(base0 + J1); \
    C##J2 = ((16383u - (u32)vo.z) << 14) | (u32)(base0 + J2); \
    C##J3 = ((16383u - (u32)vo.w) << 14) | (u32)(base0 + J3); \
    bnx = fminf(bnx, fminf(fminf(vx.x, vx.y), fminf(vx.z, vx.w))); \
    bxx = fmaxf(bxx, fmaxf(fmaxf(vx.x, vx.y), fmaxf(vx.z, vx.w))); \
    bny = fminf(bny, fminf(fminf(vy.x, vy.y), fminf(vy.z, vy.w))); \
    bxy = fmaxf(bxy, fmaxf(fmaxf(vy.x, vy.y), fmaxf(vy.z, vy.w))); \
    bnz = fminf(bnz, fminf(fminf(vz.x, vz.y), fminf(vz.z, vz.w))); \
    bxz = fmaxf(bxz, fmaxf(fmaxf(vz.x, vz.y), fmaxf(vz.z, vz.w))); }
  G4_LIST(INIT4)
#undef INIT4

  // key = md_bits<<32 | (16383-oid)<<14 | sidx (bits 31:28 zero). md >= 0 ->
  // float order == bit order. Lex max == numpy argmax (max md, tie -> min
  // oid); sidx trails.
  u64 ckey = 0;
  u64 wklast = 0;                       // per-lane dpp partial; lane 63 = wave max
  float cmaxf = 3.402823466e38f;        // forces all-active first iteration
  float cx = pos[0], cy = pos[1], cz = pos[2];
  if (t == 0) idx_out[0] = 0;
  __syncthreads();

  for (int k = 0; k < N_S - 1; ++k) {
    // ---- prune: bbox lower bound vs chunk max-min-dist. Skip-safe: if
    // 0.99*lb2 >= cmaxf no md in this chunk can decrease (1% margin >> fp32
    // rounding of 3-term sums) -> chunk state exactly unchanged.
    float dxl = fmaxf(fmaxf(bnx - cx, cx - bxx), 0.0f);
    float dyl = fmaxf(fmaxf(bny - cy, cy - bxy), 0.0f);
    float dzl = fmaxf(fmaxf(bnz - cz, cz - bxz), 0.0f);
    float lb2 = dxl * dxl + dyl * dyl + dzl * dzl;
    bool act = (0.99f * lb2 < cmaxf);

    if (__ballot(act)) {
      if (act) {
        f32x2 ncx2; ncx2.x = -cx; ncx2.y = -cx;
        f32x2 ncy2; ncy2.x = -cy; ncy2.y = -cy;
        f32x2 ncz2; ncz2.x = -cz; ncz2.y = -cz;
        u64 bkA = 0, bkB = 0;   // even/odd accumulators: halves the dep chain
        // exact numpy arithmetic per element: x+(-c) == x-c (negation exact),
        // pk mul/add are per-op RNE, association (dx2+dy2)+dz2 preserved.
        // Key build is a register-pair: ((u64)md_bits<<32)|C -> no shifts.
#define UPDP(P, J0, J1) { \
        f32x2 dx2 = pk_add(X##P, ncx2); \
        f32x2 dy2 = pk_add(Y##P, ncy2); \
        f32x2 dz2 = pk_add(Z##P, ncz2); \
        f32x2 sq = pk_add(pk_mul(dx2, dx2), pk_mul(dy2, dy2)); \
        f32x2 d2 = pk_add(sq, pk_mul(dz2, dz2)); \
        float m0 = fminf(md##J0, d2.x); md##J0 = m0; \
        bkA = u64fmax(bkA, ((u64)__float_as_uint(m0) << 32) | C##J0); \
        float m1 = fminf(md##J1, d2.y); md##J1 = m1; \
        bkB = u64fmax(bkB, ((u64)__float_as_uint(m1) << 32) | C##J1); }
        UPDP(0, 0, 1)  UPDP(1, 2, 3)  UPDP(2, 4, 5)  UPDP(3, 6, 7)
        UPDP(4, 8, 9)  UPDP(5, 10, 11) UPDP(6, 12, 13) UPDP(7, 14, 15)
#undef UPDP
        ckey = u64fmax(bkA, bkB);
        cmaxf = __uint_as_float((u32)(ckey >> 32));   // high word: free extract
      }
      // wave64 max via DPP (row_shr scan + row broadcasts): lane 63 = wave max.
      // Inactive lanes carry their old (still-valid) ckey.
      u64 wk = ckey;
      wk = dppmax<0x111, 0xf>(wk);   // row_shr:1
      wk = dppmax<0x112, 0xf>(wk);   // row_shr:2
      wk = dppmax<0x114, 0xf>(wk);   // row_shr:4
      wk = dppmax<0x118, 0xf>(wk);   // row_shr:8
      wk = dppmax<0x142, 0xa>(wk);   // row_bcast:15 -> rows 1,3
      wk = dppmax<0x143, 0xc>(wk);   // row_bcast:31 -> rows 2,3
      wklast = wk;                   // lane63's value = wave max
    }
    // publish: single-lane plain write (no RMW). Pruned waves re-publish
    // wklast (exact: their mds unchanged, md monotone non-increasing).
    if ((t & 63) == 63) s_k[k & 1][wv] = wklast;
    __syncthreads();

    // ---- all waves redundantly reduce the 16 wave keys: ONE vector b64 read
    // (16 addrs, 4x replicated broadcast, bank-sweep, conflict-free) + 4-stage
    // row_ror dppmax (period-16) -> every lane holds the global max.
    u64 gk = s_k[k & 1][t & 15];
    gk = dppmax<0x121, 0xf>(gk);   // row_ror:1
    gk = dppmax<0x122, 0xf>(gk);   // row_ror:2
    gk = dppmax<0x124, 0xf>(gk);   // row_ror:4
    gk = dppmax<0x128, 0xf>(gk);   // row_ror:8
    u32 glo = (u32)__builtin_amdgcn_readfirstlane((int)(u32)gk);
    u32 ghi = (u32)__builtin_amdgcn_readfirstlane((int)(u32)(gk >> 32));
    u64 gmax = ((u64)ghi << 32) | glo;
    int sidx = (int)(gmax & 16383u);      // SGPR (from readfirstlane chain)
    if (t == 0) idx_out[k + 1] = 16383 - (int)((gmax >> 14) & 16383u);
    // next center: cx via global load from L1/L2-resident xs (overlaps LDS);
    // cy,cz via ONE uniform broadcast b64 read from the point's LDS cell.
    int cell = (sidx & (PPT - 1)) * FPS_T + (sidx >> 4);
    cx = xs[sidx];
    float2 yz = s_yz[cell];
    cy = yz.x;
    cz = yz.y;
  }
}

// ======================= zero the tail rows [N_S, N_PTS) =======================
__global__ void zero_tail(float4* __restrict__ outv, int count) {
  int i = blockIdx.x * blockDim.x + threadIdx.x;
  if (i < count) outv[i] = make_float4(0.f, 0.f, 0.f, 0.f);
}

// ======================= kNN: 32-way split + exact lex merge =======================
// R25: (a) packed float4 tile -> 1 ds_read_b128 (2 broadcast addrs/wave,
// conflict-free) instead of 3 dependent b32; (b) 32 splits x 1024 thr ->
// 4 waves/SIMD (was 2) for latency hiding, 512 pts/thread. Merge arrays
// stride 321 (==1 mod 32, conflict-free). LDS ~98 KB -> 1 block/CU.
// Exactness: global top-10 subset of union of 32 per-split top-10s; lex-min
// (d, idx) merge identical to 8/16-way versions.
#define KNN_T  1024  // 32 centers x 32 splits
#define KNS    32
#define KTILE  1024
#define KPAD   321   // KNS*NB=320 -> pad to 321 (==1 mod 32)

__global__ __launch_bounds__(KNN_T) void knn_kernel(const float* __restrict__ pos,
                                                    const int* __restrict__ fps_idx,
                                                    int* __restrict__ src_out,
                                                    int* __restrict__ valid_out) {
  __shared__ float4 s_p[KTILE];   // packed (x,y,z,0): 16 KB
  __shared__ float spd[32][KPAD];
  __shared__ int   spi[32][KPAD];
  const int t = threadIdx.x;
  const int sp = t >> 5;          // split 0..31
  const int cl = t & 31;          // center lane 0..31
  const int i = blockIdx.x * 32 + cl;
  const int ci = fps_idx[i];
  const float cx = pos[3 * ci], cy = pos[3 * ci + 1], cz = pos[3 * ci + 2];
  float nd[NB]; int ni[NB];
#pragma unroll
  for (int q = 0; q < NB; ++q) { nd[q] = 3.402823466e38f; ni[q] = 0x7fffffff; }

  for (int base = 0; base < N_PTS; base += KTILE) {
    __syncthreads();
    for (int j = t; j < KTILE; j += KNN_T) {
      int pnt = base + j;
      s_p[j] = make_float4(pos[3 * pnt], pos[3 * pnt + 1], pos[3 * pnt + 2], 0.f);
    }
    __syncthreads();
    for (int j = sp; j < KTILE; j += KNS) {
      float4 q4 = s_p[j];
      float dx = __fsub_rn(cx, q4.x);
      float dy = __fsub_rn(cy, q4.y);
      float dz = __fsub_rn(cz, q4.z);
      float d2 = __fadd_rn(__fadd_rn(__fmul_rn(dx, dx), __fmul_rn(dy, dy)), __fmul_rn(dz, dz));
      if (d2 < nd[NB - 1]) {
        float cd = d2; int cp = base + j;
#pragma unroll
        for (int q = 0; q < NB; ++q) {
          bool sw = (cd < nd[q]) || (cd == nd[q] && cp < ni[q]);
          if (sw) { float td = nd[q]; int tp = ni[q]; nd[q] = cd; ni[q] = cp; cd = td; cp = tp; }
        }
      }
    }
  }
#pragma unroll
  for (int q = 0; q < NB; ++q) { spd[cl][sp * NB + q] = nd[q]; spi[cl][sp * NB + q] = ni[q]; }
  __syncthreads();
  if (sp == 0) {
    int cur[KNS];
#pragma unroll
    for (int s = 0; s < KNS; ++s) cur[s] = 0;
    int vb = 0;
    for (int q = 0; q < NB; ++q) {
      float bd = 3.402823466e38f; int bi = 0x7fffffff; int bsl = 0;
#pragma unroll
      for (int s = 0; s < KNS; ++s) {
        float d = spd[cl][s * NB + cur[s]]; int id = spi[cl][s * NB + cur[s]];
        if (d < bd || (d == bd && id < bi)) { bd = d; bi = id; bsl = s; }
      }
#pragma unroll
      for (int s = 0; s < KNS; ++s) cur[s] += (s == bsl) ? 1 : 0;
      src_out[i * NB + q] = bi;
      if (bd <= R2) vb |= (1 << q);
    }
    valid_out[i] = vb;
  }
}

// ======================= MLP + masked max-pool =======================
// R25: W2 transposed into LDS with stride 68 (16B-aligned b128 reads, banks
// uniformly swept: lane t covers banks [4t..4t+3] mod 32 -> minimal 8 beats).
// Inner loop: 160 ds_read_b128 (+broadcast sh1 b128) instead of 640 b32.
// Accumulation stays kk-ascending in-order fmaf (within tolerance regime).
#define MLP_T 128
#define W2S   68   // stride: multiple of 4 (alignment), !=0 mod ... bank-uniform

__global__ __launch_bounds__(MLP_T) void mlp_kernel(const float* __restrict__ pos,
                                                    const int* __restrict__ src,
                                                    const int* __restrict__ valid,
                                                    const float* __restrict__ W1,
                                                    const float* __restrict__ b1,
                                                    const float* __restrict__ W2,
                                                    const float* __restrict__ b2,
                                                    float* __restrict__ out) {
  __shared__ float sW2T[COUT * W2S];   // [c][kk] transposed, stride 68: 34.8 KB
  __shared__ float sW1[3 * CHID];
  __shared__ float sb1[CHID];
  __shared__ float sh1[NB][CHID];
  __shared__ float srel[NB][3];
  __shared__ int   svalid;
  const int t = threadIdx.x;
  const int i = blockIdx.x;

  // transpose-load W2: thread t owns output column c=t; global reads
  // W2[kk*COUT+t] are lane-coalesced for each kk.
  for (int kk = 0; kk < CHID; ++kk) sW2T[t * W2S + kk] = W2[kk * COUT + t];
  for (int e = t; e < 3 * CHID; e += MLP_T) sW1[e] = W1[e];
  if (t < CHID) sb1[t] = b1[t];
  if (t < NB) {
    int s = src[i * NB + t];
    // NOTE: reference subtracts pos_i = pos[:s] (row i), NOT the sampled center
    srel[t][0] = pos[3 * s + 0] - pos[3 * i + 0];
    srel[t][1] = pos[3 * s + 1] - pos[3 * i + 1];
    srel[t][2] = pos[3 * s + 2] - pos[3 * i + 2];
  }
  if (t == 0) svalid = valid[i];
  __syncthreads();

  for (int e = t; e < NB * CHID; e += MLP_T) {
    int n = e >> 6, kk = e & 63;
    float a = sb1[kk] + srel[n][0] * sW1[kk] + srel[n][1] * sW1[64 + kk] + srel[n][2] * sW1[128 + kk];
    sh1[n][kk] = fmaxf(a, 0.0f);
  }
  __syncthreads();

  const int vmask = svalid;
  const float bb = b2[t];
  float m = 0.0f;
  bool any = false;
  for (int n = 0; n < NB; ++n) {
    if (vmask & (1 << n)) {
      float acc = bb;
#pragma unroll
      for (int kk = 0; kk < CHID; kk += 4) {
        float4 w = *(const float4*)&sW2T[t * W2S + kk];
        float4 h = *(const float4*)&sh1[n][kk];
        acc = fmaf(h.x, w.x, acc);
        acc = fmaf(h.y, w.y, acc);
        acc = fmaf(h.z, w.z, acc);
        acc = fmaf(h.w, w.w, acc);
      }
      m = any ? fmaxf(m, acc) : acc;
      any = true;
    }
  }
  out[i * COUT + t] = any ? m : 0.0f;
}

// ======================= launch =======================
extern "C" void kernel_launch(void* const* d_in, const int* in_sizes, int n_in,
                              void* d_out, int out_size, void* d_ws, size_t ws_size,
                              hipStream_t stream) {
  (void)in_sizes; (void)n_in; (void)out_size; (void)ws_size;
  const float* pos = (const float*)d_in[0];
  const float* W1 = (const float*)d_in[2];
  const float* b1 = (const float*)d_in[3];
  const float* W2 = (const float*)d_in[4];
  const float* b2 = (const float*)d_in[5];
  float* out = (float*)d_out;

  char* ws = (char*)d_ws;
  int*   idx   = (int*)ws;                 ws += (size_t)N_S * 4;          // 32 KB
  int*   src   = (int*)ws;                 ws += (size_t)N_S * NB * 4;     // 320 KB
  int*   valid = (int*)ws;                 ws += (size_t)N_S * 4;          // 32 KB
  float* xs    = (float*)ws;               ws += (size_t)N_PTS * 4;        // 64 KB
  float* ys    = (float*)ws;               ws += (size_t)N_PTS * 4;
  float* zs    = (float*)ws;               ws += (size_t)N_PTS * 4;
  int*   oid   = (int*)ws;                 ws += (size_t)N_PTS * 4;
  // sort temporaries alias the src region (sort completes before knn writes src)
  int* cellid = src;                 // N_PTS ints = 64 KB  (src region is 320 KB)
  int* hist   = src + N_PTS;         // NCELL ints = 16 KB
  int* basebuf= src + N_PTS + NCELL; // NCELL ints = 16 KB

  zero_hist<<<NCELL / 256, 256, 0, stream>>>(hist);
  cell_kernel<<<N_PTS / 256, 256, 0, stream>>>(pos, cellid, hist);
  scan_kernel<<<1, 1024, 0, stream>>>(hist, basebuf);
  scatter_kernel<<<N_PTS / 256, 256, 0, stream>>>(pos, cellid, basebuf, xs, ys, zs, oid);
  fps_kernel<<<1, FPS_T, 0, stream>>>(pos, xs, ys, zs, oid, idx);
  {
    int count = (N_PTS - N_S) * COUT / 4;
    zero_tail<<<(count + 255) / 256, 256, 0, stream>>>((float4*)(out + (size_t)N_S * COUT), count);
  }
  knn_kernel<<<N_S / 32, KNN_T, 0, stream>>>(pos, idx, src, valid);
  mlp_kernel<<<N_S, MLP_T, 0, stream>>>(pos, src, valid, W1, b1, W2, b2, out);
}

// Round 10
// 7189.626 us; speedup vs baseline: 1.2013x; 1.0074x over previous
//
#include <hip/hip_runtime.h>

typedef unsigned int u32;
typedef unsigned long long u64;
typedef float f32x2 __attribute__((ext_vector_type(2)));

#define N_PTS 16384
#define N_S   8192
#define NB    10
#define CHID  64
#define COUT  128
#define R2    0.0625f
#define NCELL 4096

// ======================= sort: morton counting sort =======================
__device__ __forceinline__ u32 spread3(u32 v) {  // 4 bits -> every 3rd bit
  return (v & 1u) | ((v & 2u) << 2) | ((v & 4u) << 4) | ((v & 8u) << 6);
}

__global__ void cell_kernel(const float* __restrict__ pos, int* __restrict__ cellid,
                            int* __restrict__ hist) {
  int i = blockIdx.x * 256 + threadIdx.x;
  float x = pos[3 * i], y = pos[3 * i + 1], z = pos[3 * i + 2];
  u32 ix = (u32)(x * 16.0f); if (ix > 15u) ix = 15u;
  u32 iy = (u32)(y * 16.0f); if (iy > 15u) iy = 15u;
  u32 iz = (u32)(z * 16.0f); if (iz > 15u) iz = 15u;
  u32 c = spread3(ix) | (spread3(iy) << 1) | (spread3(iz) << 2);
  cellid[i] = (int)c;
  atomicAdd(&hist[c], 1);
}

__global__ __launch_bounds__(1024) void scan_kernel(const int* __restrict__ hist,
                                                    int* __restrict__ base) {
  __shared__ int sp[1024];
  int t = threadIdx.x;
  int h0 = hist[4 * t], h1 = hist[4 * t + 1], h2 = hist[4 * t + 2], h3 = hist[4 * t + 3];
  int s = h0 + h1 + h2 + h3;
  int acc = s;
  sp[t] = s;
  __syncthreads();
  for (int off = 1; off < 1024; off <<= 1) {
    int v = (t >= off) ? sp[t - off] : 0;
    __syncthreads();
    acc += v;
    sp[t] = acc;
    __syncthreads();
  }
  int excl = acc - s;
  base[4 * t + 0] = excl;
  base[4 * t + 1] = excl + h0;
  base[4 * t + 2] = excl + h0 + h1;
  base[4 * t + 3] = excl + h0 + h1 + h2;
}

__global__ void scatter_kernel(const float* __restrict__ pos, const int* __restrict__ cellid,
                               int* __restrict__ base, float* __restrict__ xs,
                               float* __restrict__ ys, float* __restrict__ zs,
                               int* __restrict__ oid) {
  int i = blockIdx.x * 256 + threadIdx.x;
  int c = cellid[i];
  int d = atomicAdd(&base[c], 1);
  xs[d] = pos[3 * i]; ys[d] = pos[3 * i + 1]; zs[d] = pos[3 * i + 2];
  oid[d] = i;
}

// ======================= W2 transpose precompute (once) =======================
// W2T[(g*COUT + c)*4 + j] = W2[(4g+j)*COUT + c]  (g 0..15, c 0..127)
// Both sides coalesced; lets mlp threads load their weight column as 16
// consecutive-per-lane float4s.
__global__ void transpose_w2(const float* __restrict__ W2, float* __restrict__ W2T) {
  int idx = blockIdx.x * 256 + threadIdx.x;   // 2048 total
  int c = idx & (COUT - 1);
  int g = idx >> 7;
  float4 v;
  v.x = W2[(4 * g + 0) * COUT + c];
  v.y = W2[(4 * g + 1) * COUT + c];
  v.z = W2[(4 * g + 2) * COUT + c];
  v.w = W2[(4 * g + 3) * COUT + c];
  ((float4*)W2T)[g * COUT + c] = v;
}

// ======================= FPS: R24 frozen (6.57 ms verified) ==================
// R26 floor audit: ~4770 cy/CU/iter VALU issue = ~11 active wave-bodies x
// ~280cy + 16x~100cy fixed. Body = 8 pk (minimal exact d2) + 2 fmin +
// 2 max_f64 + pair-build keys; v_pk_min_f32 does NOT exist on CDNA (only
// pk add/mul/fma) -> no further packing. Activity is structural (wave-OR of
// lane prune, Morton-clustered). Multi-CU needs 8191 grid syncs -> worse.
// FPS FROZEN.
#define FPS_T 1024
#define PPT   16

#define PT_LIST(OP) OP(0) OP(1) OP(2) OP(3) OP(4) OP(5) OP(6) OP(7) \
                    OP(8) OP(9) OP(10) OP(11) OP(12) OP(13) OP(14) OP(15)
// OP(G, J0,J1,J2,J3, PA,PB): float4 group G covers points 4G..4G+3, pairs PA=2G, PB=2G+1
#define G4_LIST(OP) OP(0,0,1,2,3,0,1)   OP(1,4,5,6,7,2,3) \
                    OP(2,8,9,10,11,4,5) OP(3,12,13,14,15,6,7)
#define PR_LIST(OP) OP(0) OP(1) OP(2) OP(3) OP(4) OP(5) OP(6) OP(7)

// u64 max via positive-double max (key high word = finite positive float bits
// -> double exponent never all-ones, sign 0; positive doubles order == bit
// order).
__device__ __forceinline__ u64 u64fmax(u64 a, u64 b) {
  double ad = __longlong_as_double((long long)a);
  double bd = __longlong_as_double((long long)b);
  return (u64)(long long)__double_as_longlong(fmax(ad, bd));
}

template <int CTRL, int RM>
__device__ __forceinline__ u64 dppmax(u64 cur) {
  int slo = __builtin_amdgcn_update_dpp(0, (int)(u32)cur, CTRL, RM, 0xf, false);
  int shi = __builtin_amdgcn_update_dpp(0, (int)(u32)(cur >> 32), CTRL, RM, 0xf, false);
  u64 o = ((u64)(u32)shi << 32) | (u32)slo;
  return u64fmax(o, cur);
}

// packed 2xf32 ops (VOP3P, gfx90a+). IEEE RNE per element, no contraction
// possible (opaque asm), denorm mode identical to scalar VALU.
__device__ __forceinline__ f32x2 pk_add(f32x2 a, f32x2 b) {
  f32x2 d;
  asm("v_pk_add_f32 %0, %1, %2" : "=v"(d) : "v"(a), "v"(b));
  return d;
}
__device__ __forceinline__ f32x2 pk_mul(f32x2 a, f32x2 b) {
  f32x2 d;
  asm("v_pk_mul_f32 %0, %1, %2" : "=v"(d) : "v"(a), "v"(b));
  return d;
}

__global__ __launch_bounds__(FPS_T, 4)
void fps_kernel(const float* __restrict__ pos,
                const float* __restrict__ xs,
                const float* __restrict__ ys,
                const float* __restrict__ zs,
                const int* __restrict__ oidv,
                int* __restrict__ idx_out) {
  __shared__ float2 s_yz[PPT * FPS_T];      // [j][t] (y,z): 128 KB (center fetch only)
  __shared__ u64 s_k[2][16];                // parity double-buffer of wave keys
  const int t = threadIdx.x;
  const int wv = t >> 6;
  const int base0 = t * PPT;
  const float4* __restrict__ xv = (const float4*)(xs + base0);
  const float4* __restrict__ yv = (const float4*)(ys + base0);
  const float4* __restrict__ zv = (const float4*)(zs + base0);
  const int4*   __restrict__ ov = (const int4*)(oidv + base0);

  // ---- per-point register state: md, x/y/z pairs, key low-word constants
#define DECLP(J) float md##J;
  PT_LIST(DECLP)
#undef DECLP
#define DECLC(J) u32 C##J;
  PT_LIST(DECLC)
#undef DECLC
#define DECLX(P) f32x2 X##P; f32x2 Y##P; f32x2 Z##P;
  PR_LIST(DECLX)
#undef DECLX

  // lane-private chunk bbox lives in registers (constant after init)
  float bnx = 3.4e38f, bxx = -3.4e38f, bny = 3.4e38f, bxy = -3.4e38f,
        bnz = 3.4e38f, bxz = -3.4e38f;

#define INIT4(G, J0, J1, J2, J3, PA, PB) { \
    float4 vx = xv[G], vy = yv[G], vz = zv[G]; int4 vo = ov[G]; \
    md##J0 = 3.402823466e38f; md##J1 = 3.402823466e38f; \
    md##J2 = 3.402823466e38f; md##J3 = 3.402823466e38f; \
    X##PA.x = vx.x; X##PA.y = vx.y; X##PB.x = vx.z; X##PB.y = vx.w; \
    Y##PA.x = vy.x; Y##PA.y = vy.y; Y##PB.x = vy.z; Y##PB.y = vy.w; \
    Z##PA.x = vz.x; Z##PA.y = vz.y; Z##PB.x = vz.z; Z##PB.y = vz.w; \
    s_yz[J0 * FPS_T + t] = make_float2(vy.x, vz.x); \
    s_yz[J1 * FPS_T + t] = make_float2(vy.y, vz.y); \
    s_yz[J2 * FPS_T + t] = make_float2(vy.z, vz.z); \
    s_yz[J3 * FPS_T + t] = make_float2(vy.w, vz.w); \
    C##J0 = ((16383u - (u32)vo.x) << 14) | (u32)(base0 + J0); \
    C##J1 = ((16383u - (u32)vo.y) << 14) | (u32)(base0 + J1); \
    C##J2 = ((16383u - (u32)vo.z) << 14) | (u32)(base0 + J2); \
    C##J3 = ((16383u - (u32)vo.w) << 14) | (u32)(base0 + J3); \
    bnx = fminf(bnx, fminf(fminf(vx.x, vx.y), fminf(vx.z, vx.w))); \
    bxx = fmaxf(bxx, fmaxf(fmaxf(vx.x, vx.y), fmaxf(vx.z, vx.w))); \
    bny = fminf(bny, fminf(fminf(vy.x, vy.y), fminf(vy.z, vy.w))); \
    bxy = fmaxf(bxy, fmaxf(fmaxf(vy.x, vy.y), fmaxf(vy.z, vy.w))); \
    bnz = fminf(bnz, fminf(fminf(vz.x, vz.y), fminf(vz.z, vz.w))); \
    bxz = fmaxf(bxz, fmaxf(fmaxf(vz.x, vz.y), fmaxf(vz.z, vz.w))); }
  G4_LIST(INIT4)
#undef INIT4

  // key = md_bits<<32 | (16383-oid)<<14 | sidx (bits 31:28 zero). md >= 0 ->
  // float order == bit order. Lex max == numpy argmax (max md, tie -> min
  // oid); sidx trails.
  u64 ckey = 0;
  u64 wklast = 0;                       // per-lane dpp partial; lane 63 = wave max
  float cmaxf = 3.402823466e38f;        // forces all-active first iteration
  float cx = pos[0], cy = pos[1], cz = pos[2];
  if (t == 0) idx_out[0] = 0;
  __syncthreads();

  for (int k = 0; k < N_S - 1; ++k) {
    // ---- prune: bbox lower bound vs chunk max-min-dist. Skip-safe: if
    // 0.99*lb2 >= cmaxf no md in this chunk can decrease (1% margin >> fp32
    // rounding of 3-term sums) -> chunk state exactly unchanged.
    float dxl = fmaxf(fmaxf(bnx - cx, cx - bxx), 0.0f);
    float dyl = fmaxf(fmaxf(bny - cy, cy - bxy), 0.0f);
    float dzl = fmaxf(fmaxf(bnz - cz, cz - bxz), 0.0f);
    float lb2 = dxl * dxl + dyl * dyl + dzl * dzl;
    bool act = (0.99f * lb2 < cmaxf);

    if (__ballot(act)) {
      if (act) {
        f32x2 ncx2; ncx2.x = -cx; ncx2.y = -cx;
        f32x2 ncy2; ncy2.x = -cy; ncy2.y = -cy;
        f32x2 ncz2; ncz2.x = -cz; ncz2.y = -cz;
        u64 bkA = 0, bkB = 0;   // even/odd accumulators: halves the dep chain
        // exact numpy arithmetic per element: x+(-c) == x-c (negation exact),
        // pk mul/add are per-op RNE, association (dx2+dy2)+dz2 preserved.
        // Key build is a register-pair: ((u64)md_bits<<32)|C -> no shifts.
#define UPDP(P, J0, J1) { \
        f32x2 dx2 = pk_add(X##P, ncx2); \
        f32x2 dy2 = pk_add(Y##P, ncy2); \
        f32x2 dz2 = pk_add(Z##P, ncz2); \
        f32x2 sq = pk_add(pk_mul(dx2, dx2), pk_mul(dy2, dy2)); \
        f32x2 d2 = pk_add(sq, pk_mul(dz2, dz2)); \
        float m0 = fminf(md##J0, d2.x); md##J0 = m0; \
        bkA = u64fmax(bkA, ((u64)__float_as_uint(m0) << 32) | C##J0); \
        float m1 = fminf(md##J1, d2.y); md##J1 = m1; \
        bkB = u64fmax(bkB, ((u64)__float_as_uint(m1) << 32) | C##J1); }
        UPDP(0, 0, 1)  UPDP(1, 2, 3)  UPDP(2, 4, 5)  UPDP(3, 6, 7)
        UPDP(4, 8, 9)  UPDP(5, 10, 11) UPDP(6, 12, 13) UPDP(7, 14, 15)
#undef UPDP
        ckey = u64fmax(bkA, bkB);
        cmaxf = __uint_as_float((u32)(ckey >> 32));   // high word: free extract
      }
      // wave64 max via DPP (row_shr scan + row broadcasts): lane 63 = wave max.
      // Inactive lanes carry their old (still-valid) ckey.
      u64 wk = ckey;
      wk = dppmax<0x111, 0xf>(wk);   // row_shr:1
      wk = dppmax<0x112, 0xf>(wk);   // row_shr:2
      wk = dppmax<0x114, 0xf>(wk);   // row_shr:4
      wk = dppmax<0x118, 0xf>(wk);   // row_shr:8
      wk = dppmax<0x142, 0xa>(wk);   // row_bcast:15 -> rows 1,3
      wk = dppmax<0x143, 0xc>(wk);   // row_bcast:31 -> rows 2,3
      wklast = wk;                   // lane63's value = wave max
    }
    // publish: single-lane plain write (no RMW). Pruned waves re-publish
    // wklast (exact: their mds unchanged, md monotone non-increasing).
    if ((t & 63) == 63) s_k[k & 1][wv] = wklast;
    __syncthreads();

    // ---- all waves redundantly reduce the 16 wave keys: ONE vector b64 read
    // (16 addrs, 4x replicated broadcast, bank-sweep, conflict-free) + 4-stage
    // row_ror dppmax (period-16) -> every lane holds the global max.
    u64 gk = s_k[k & 1][t & 15];
    gk = dppmax<0x121, 0xf>(gk);   // row_ror:1
    gk = dppmax<0x122, 0xf>(gk);   // row_ror:2
    gk = dppmax<0x124, 0xf>(gk);   // row_ror:4
    gk = dppmax<0x128, 0xf>(gk);   // row_ror:8
    u32 glo = (u32)__builtin_amdgcn_readfirstlane((int)(u32)gk);
    u32 ghi = (u32)__builtin_amdgcn_readfirstlane((int)(u32)(gk >> 32));
    u64 gmax = ((u64)ghi << 32) | glo;
    int sidx = (int)(gmax & 16383u);      // SGPR (from readfirstlane chain)
    if (t == 0) idx_out[k + 1] = 16383 - (int)((gmax >> 14) & 16383u);
    // next center: cx via global load from L1/L2-resident xs (overlaps LDS);
    // cy,cz via ONE uniform broadcast b64 read from the point's LDS cell.
    int cell = (sidx & (PPT - 1)) * FPS_T + (sidx >> 4);
    cx = xs[sidx];
    float2 yz = s_yz[cell];
    cy = yz.x;
    cz = yz.y;
  }
}

// ======================= zero the tail rows [N_S, N_PTS) =======================
__global__ void zero_tail(float4* __restrict__ outv, int count) {
  int i = blockIdx.x * blockDim.x + threadIdx.x;
  if (i < count) outv[i] = make_float4(0.f, 0.f, 0.f, 0.f);
}

// ======================= kNN: 32-way split + exact lex merge (R25 frozen) ======
#define KNN_T  1024  // 32 centers x 32 splits
#define KNS    32
#define KTILE  1024
#define KPAD   321   // KNS*NB=320 -> pad to 321 (==1 mod 32)

__global__ __launch_bounds__(KNN_T) void knn_kernel(const float* __restrict__ pos,
                                                    const int* __restrict__ fps_idx,
                                                    int* __restrict__ src_out,
                                                    int* __restrict__ valid_out) {
  __shared__ float4 s_p[KTILE];   // packed (x,y,z,0): 16 KB
  __shared__ float spd[32][KPAD];
  __shared__ int   spi[32][KPAD];
  const int t = threadIdx.x;
  const int sp = t >> 5;          // split 0..31
  const int cl = t & 31;          // center lane 0..31
  const int i = blockIdx.x * 32 + cl;
  const int ci = fps_idx[i];
  const float cx = pos[3 * ci], cy = pos[3 * ci + 1], cz = pos[3 * ci + 2];
  float nd[NB]; int ni[NB];
#pragma unroll
  for (int q = 0; q < NB; ++q) { nd[q] = 3.402823466e38f; ni[q] = 0x7fffffff; }

  for (int base = 0; base < N_PTS; base += KTILE) {
    __syncthreads();
    for (int j = t; j < KTILE; j += KNN_T) {
      int pnt = base + j;
      s_p[j] = make_float4(pos[3 * pnt], pos[3 * pnt + 1], pos[3 * pnt + 2], 0.f);
    }
    __syncthreads();
    for (int j = sp; j < KTILE; j += KNS) {
      float4 q4 = s_p[j];
      float dx = __fsub_rn(cx, q4.x);
      float dy = __fsub_rn(cy, q4.y);
      float dz = __fsub_rn(cz, q4.z);
      float d2 = __fadd_rn(__fadd_rn(__fmul_rn(dx, dx), __fmul_rn(dy, dy)), __fmul_rn(dz, dz));
      if (d2 < nd[NB - 1]) {
        float cd = d2; int cp = base + j;
#pragma unroll
        for (int q = 0; q < NB; ++q) {
          bool sw = (cd < nd[q]) || (cd == nd[q] && cp < ni[q]);
          if (sw) { float td = nd[q]; int tp = ni[q]; nd[q] = cd; ni[q] = cp; cd = td; cp = tp; }
        }
      }
    }
  }
#pragma unroll
  for (int q = 0; q < NB; ++q) { spd[cl][sp * NB + q] = nd[q]; spi[cl][sp * NB + q] = ni[q]; }
  __syncthreads();
  if (sp == 0) {
    int cur[KNS];
#pragma unroll
    for (int s = 0; s < KNS; ++s) cur[s] = 0;
    int vb = 0;
    for (int q = 0; q < NB; ++q) {
      float bd = 3.402823466e38f; int bi = 0x7fffffff; int bsl = 0;
#pragma unroll
      for (int s = 0; s < KNS; ++s) {
        float d = spd[cl][s * NB + cur[s]]; int id = spi[cl][s * NB + cur[s]];
        if (d < bd || (d == bd && id < bi)) { bd = d; bi = id; bsl = s; }
      }
#pragma unroll
      for (int s = 0; s < KNS; ++s) cur[s] += (s == bsl) ? 1 : 0;
      src_out[i * NB + q] = bi;
      if (bd <= R2) vb |= (1 << q);
    }
    valid_out[i] = vb;
  }
}

// ======================= MLP + masked max-pool =======================
// R26: weight column in 64 VGPRs via 16 coalesced float4 loads from the
// precomputed W2T (L2-resident after first block). Removes the per-block
// 64-load transpose + 35 KB sW2T + one barrier dependency; LDS ~3 KB ->
// occupancy bounded by waves, not LDS. Accumulation order identical to R25
// (kk-ascending fmaf) -> bit-identical output.
#define MLP_T 128

__global__ __launch_bounds__(MLP_T) void mlp_kernel(const float* __restrict__ pos,
                                                    const int* __restrict__ src,
                                                    const int* __restrict__ valid,
                                                    const float* __restrict__ W1,
                                                    const float* __restrict__ b1,
                                                    const float* __restrict__ W2T,
                                                    const float* __restrict__ b2,
                                                    float* __restrict__ out) {
  __shared__ float sW1[3 * CHID];
  __shared__ float sb1[CHID];
  __shared__ float sh1[NB][CHID];
  __shared__ float srel[NB][3];
  __shared__ int   svalid;
  const int t = threadIdx.x;
  const int i = blockIdx.x;

  // weight column for output channel t: 16 float4, lane-consecutive -> coalesced
  float4 w[16];
#pragma unroll
  for (int g = 0; g < 16; ++g) w[g] = ((const float4*)W2T)[g * COUT + t];

  for (int e = t; e < 3 * CHID; e += MLP_T) sW1[e] = W1[e];
  if (t < CHID) sb1[t] = b1[t];
  if (t < NB) {
    int s = src[i * NB + t];
    // NOTE: reference subtracts pos_i = pos[:s] (row i), NOT the sampled center
    srel[t][0] = pos[3 * s + 0] - pos[3 * i + 0];
    srel[t][1] = pos[3 * s + 1] - pos[3 * i + 1];
    srel[t][2] = pos[3 * s + 2] - pos[3 * i + 2];
  }
  if (t == 0) svalid = valid[i];
  __syncthreads();

  for (int e = t; e < NB * CHID; e += MLP_T) {
    int n = e >> 6, kk = e & 63;
    float a = sb1[kk] + srel[n][0] * sW1[kk] + srel[n][1] * sW1[64 + kk] + srel[n][2] * sW1[128 + kk];
    sh1[n][kk] = fmaxf(a, 0.0f);
  }
  __syncthreads();

  const int vmask = svalid;
  const float bb = b2[t];
  float m = 0.0f;
  bool any = false;
  for (int n = 0; n < NB; ++n) {
    if (vmask & (1 << n)) {
      float acc = bb;
#pragma unroll
      for (int g = 0; g < 16; ++g) {
        float4 h = *(const float4*)&sh1[n][4 * g];
        acc = fmaf(h.x, w[g].x, acc);
        acc = fmaf(h.y, w[g].y, acc);
        acc = fmaf(h.z, w[g].z, acc);
        acc = fmaf(h.w, w[g].w, acc);
      }
      m = any ? fmaxf(m, acc) : acc;
      any = true;
    }
  }
  out[i * COUT + t] = any ? m : 0.0f;
}

// ======================= launch =======================
extern "C" void kernel_launch(void* const* d_in, const int* in_sizes, int n_in,
                              void* d_out, int out_size, void* d_ws, size_t ws_size,
                              hipStream_t stream) {
  (void)in_sizes; (void)n_in; (void)out_size; (void)ws_size;
  const float* pos = (const float*)d_in[0];
  const float* W1 = (const float*)d_in[2];
  const float* b1 = (const float*)d_in[3];
  const float* W2 = (const float*)d_in[4];
  const float* b2 = (const float*)d_in[5];
  float* out = (float*)d_out;

  char* ws = (char*)d_ws;
  int*   idx   = (int*)ws;                 ws += (size_t)N_S * 4;          // 32 KB
  int*   src   = (int*)ws;                 ws += (size_t)N_S * NB * 4;     // 320 KB
  int*   valid = (int*)ws;                 ws += (size_t)N_S * 4;          // 32 KB
  float* xs    = (float*)ws;               ws += (size_t)N_PTS * 4;        // 64 KB
  float* ys    = (float*)ws;               ws += (size_t)N_PTS * 4;
  float* zs    = (float*)ws;               ws += (size_t)N_PTS * 4;
  int*   oid   = (int*)ws;                 ws += (size_t)N_PTS * 4;
  float* w2t   = (float*)ws;               ws += (size_t)CHID * COUT * 4;  // 32 KB
  // sort temporaries alias the src region (sort completes before knn writes src)
  int* cellid = src;                 // N_PTS ints = 64 KB  (src region is 320 KB)
  int* hist   = src + N_PTS;         // NCELL ints = 16 KB
  int* basebuf= src + N_PTS + NCELL; // NCELL ints = 16 KB

  hipMemsetAsync(hist, 0, (size_t)NCELL * 4, stream);
  cell_kernel<<<N_PTS / 256, 256, 0, stream>>>(pos, cellid, hist);
  scan_kernel<<<1, 1024, 0, stream>>>(hist, basebuf);
  scatter_kernel<<<N_PTS / 256, 256, 0, stream>>>(pos, cellid, basebuf, xs, ys, zs, oid);
  transpose_w2<<<CHID * COUT / (4 * 256), 256, 0, stream>>>(W2, w2t);
  fps_kernel<<<1, FPS_T, 0, stream>>>(pos, xs, ys, zs, oid, idx);
  {
    int count = (N_PTS - N_S) * COUT / 4;
    zero_tail<<<(count + 255) / 256, 256, 0, stream>>>((float4*)(out + (size_t)N_S * COUT), count);
  }
  knn_kernel<<<N_S / 32, KNN_T, 0, stream>>>(pos, idx, src, valid);
  mlp_kernel<<<N_S, MLP_T, 0, stream>>>(pos, src, valid, W1, b1, w2t, b2, out);
}